// Round 3
// baseline (333.883 us; speedup 1.0000x reference)
//
#include <hip/hip_runtime.h>
#include <math.h>

#define NODES 20000
#define MPAD  20096          // NODES padded to multiple of 128 (GEMM M-tiles)
#define EDGES 320000
#define EPSV  1e-5f
#define LOG2E 1.4426950408889634f

// k_prep block ranges
#define PREP_CNT   1250                    // count: 1250*256 >= EDGES
#define PREP_CAST  5000                    // cast: NODES*256/4/256
#define PREP_TR    512                     // 4 matrices * 128 tiles
#define PREP_TOTAL (PREP_CNT + PREP_CAST + PREP_TR + 1)

typedef short bf16x8 __attribute__((ext_vector_type(8)));
typedef float f32x4  __attribute__((ext_vector_type(4)));
typedef float f2     __attribute__((ext_vector_type(2)));

__device__ __forceinline__ unsigned short f2bf(float f) {
    unsigned int u = __float_as_uint(f);
    u = (u + 0x7fffu + ((u >> 16) & 1u)) >> 16;
    return (unsigned short)u;
}
__device__ __forceinline__ float bf2f(unsigned short h) {
    return __uint_as_float(((unsigned int)h) << 16);
}

// async global->LDS, 16B per lane; lds dest = wave-uniform base + lane*16
__device__ __forceinline__ void load_lds16(const unsigned short* g, unsigned short* l) {
    __builtin_amdgcn_global_load_lds(
        (const __attribute__((address_space(1))) unsigned int*)g,
        (__attribute__((address_space(3))) unsigned int*)l, 16, 0, 0);
}

// ---------------- fused prep: edge-count + x cast + 4x weight transpose + zeros
__global__ void k_prep(const int* __restrict__ dst, int* __restrict__ counts,
                       const float* __restrict__ x, unsigned short* __restrict__ xb,
                       const float* __restrict__ Wl1, const float* __restrict__ Wr1,
                       const float* __restrict__ Wl2, const float* __restrict__ Wr2,
                       unsigned short* __restrict__ o1l, unsigned short* __restrict__ o1r,
                       unsigned short* __restrict__ o2l, unsigned short* __restrict__ o2r,
                       float* __restrict__ acc, float* __restrict__ colsum) {
    int b = blockIdx.x;
    int t = threadIdx.x;
    if (b < PREP_CNT) {
        int e = b * 256 + t;
        if (e < EDGES) atomicAdd(&counts[dst[e]], 1);
    } else if (b < PREP_CNT + PREP_CAST) {
        int i = ((b - PREP_CNT) * 256 + t) * 4;
        float4 v = *(const float4*)(x + i);
        xb[i + 0] = f2bf(v.x); xb[i + 1] = f2bf(v.y);
        xb[i + 2] = f2bf(v.z); xb[i + 3] = f2bf(v.w);
    } else if (b < PREP_CNT + PREP_CAST + PREP_TR) {
        __shared__ float tile[32][33];
        int zz = b - PREP_CNT - PREP_CAST;     // 0..511
        int z = zz >> 7;                        // matrix 0..3
        int idx = zz & 127;                     // tile within matrix
        const float* W = (z == 0) ? Wl1 : (z == 1) ? Wr1 : (z == 2) ? Wl2 : Wr2;
        unsigned short* Wt = (z == 0) ? o1l : (z == 1) ? o1r : (z == 2) ? o2l : o2r;
        int K = (z < 2) ? 256 : 512, N = (z < 2) ? 512 : 256;
        int nb = N / 32;
        int n0 = (idx % nb) * 32, k0 = (idx / nb) * 32;
        int tx = t & 31, ty = t >> 5;          // (32,8) layout
#pragma unroll
        for (int j = 0; j < 4; j++)
            tile[ty + j * 8][tx] = W[(size_t)(k0 + ty + j * 8) * N + n0 + tx];
        __syncthreads();
#pragma unroll
        for (int j = 0; j < 4; j++)
            Wt[(size_t)(n0 + ty + j * 8) * K + k0 + tx] = f2bf(tile[tx][ty + j * 8]);
    } else {
        if (t < 4) acc[t] = 0.f;
        colsum[t] = 0.f;
    }
}

// ---------------- single-dispatch CSR scan (1 block, 1024 thr, 20 nodes/thr) -
// Replaces the 3-dispatch hierarchical scan: same parallelism for this tiny
// array (80KB, L2-resident), minus two launches. 16 waves on one CU hide the
// 20-iteration per-thread walks.
#define SCAN_PN 20   // 1024*20 = 20480 >= NODES

__global__ __launch_bounds__(1024) void k_scan(const int* __restrict__ counts,
                                               int* __restrict__ offs) {
    __shared__ int sm[1024];
    int t = threadIdx.x;
    int i0 = t * SCAN_PN;
    int c[SCAN_PN];
    int s = 0;
#pragma unroll
    for (int j = 0; j < SCAN_PN; j++) {
        int i = i0 + j;
        c[j] = (i < NODES) ? counts[i] : 0;
        s += c[j];
    }
    sm[t] = s;
    __syncthreads();
    int v = s;
    for (int o = 1; o < 1024; o <<= 1) {
        int add = (t >= o) ? sm[t - o] : 0;
        __syncthreads();
        v += add;
        sm[t] = v;
        __syncthreads();
    }
    int run = v - s;
    if (t == 1023) offs[NODES] = v;
#pragma unroll
    for (int j = 0; j < SCAN_PN; j++) {
        int i = i0 + j;
        if (i < NODES) { offs[i] = run; run += c[j]; }
    }
}

__global__ void k_scatter(const int* __restrict__ src, const int* __restrict__ dst,
                          const int* __restrict__ offs, int* __restrict__ cursor,
                          int* __restrict__ csr_src) {
    int e = blockIdx.x * blockDim.x + threadIdx.x;
    if (e < EDGES) {
        int d = dst[e];
        int pos = atomicAdd(&cursor[d], 1);
        csr_src[offs[d] + pos] = src[e];
    }
}

// ------- per-channel softmax aggregation, un-stabilized (inputs bounded) -----
// S waves per node (interleaved waveg%S — measured fastest agg variant, r10).
// Wave-uniform CSR walk via readfirstlane: csr[k] -> s_load; vector pipe:
// loop-invariant-offset gather + packed-f32 exp2/fma.
// Measured floor ~44.5us (layer 2): 9 structural variants land 44-50us
// (incl. XCD-pinned channel slicing: fetch 133->60MB but time +2us — the
// kernel is issue/latency-bound, NOT fetch-bound; keep this config).
template <int C, int S, int UNR>
__global__ void k_agg(const unsigned short* __restrict__ xb, const float* __restrict__ tt,
                      const int* __restrict__ offs, const int* __restrict__ csr,
                      unsigned short* __restrict__ out) {
    constexpr int CS  = C / S;
    constexpr int VPL = CS / 64;
    constexpr int W   = VPL / 2;
    typedef unsigned int uv __attribute__((ext_vector_type(W)));
    typedef unsigned short usv __attribute__((ext_vector_type(VPL)));
    int waveg = (int)((blockIdx.x * (unsigned)blockDim.x + threadIdx.x) >> 6);
    int lane = threadIdx.x & 63;
    int node = waveg / S;
    int slice = waveg % S;
    if (node >= NODES) return;
    int beg = __builtin_amdgcn_readfirstlane(offs[node]);
    int end = __builtin_amdgcn_readfirstlane(offs[node + 1]);
    int cb = slice * CS + lane * VPL;
    const unsigned short* __restrict__ xcb = xb + cb;
    f2 tl[W], l[W], s[W];
#pragma unroll
    for (int i = 0; i < W; i++) {
        tl[i][0] = tt[cb + 2 * i] * LOG2E;
        tl[i][1] = tt[cb + 2 * i + 1] * LOG2E;
        l[i][0] = 0.f; l[i][1] = 0.f;
        s[i][0] = 0.f; s[i][1] = 0.f;
    }
    int k = beg;
    for (; k + UNR <= end; k += UNR) {
        uv v[UNR];
#pragma unroll
        for (int u = 0; u < UNR; u++) {
            int sn = csr[k + u];                     // uniform -> s_load
            v[u] = *(const uv*)(xcb + (size_t)sn * C);
        }
#pragma unroll
        for (int u = 0; u < UNR; u++)
#pragma unroll
            for (int i = 0; i < W; i++) {
                unsigned wd = v[u][i];
                f2 xv;
                xv[0] = __uint_as_float(wd << 16);
                xv[1] = __uint_as_float(wd & 0xffff0000u);
                f2 a = xv * tl[i];
                f2 p;
                p[0] = __builtin_amdgcn_exp2f(a[0]);
                p[1] = __builtin_amdgcn_exp2f(a[1]);
                l[i] += p;
                s[i] = __builtin_elementwise_fma(p, xv, s[i]);
            }
    }
    for (; k < end; k++) {
        int sn = csr[k];
        uv vv = *(const uv*)(xcb + (size_t)sn * C);
#pragma unroll
        for (int i = 0; i < W; i++) {
            unsigned wd = vv[i];
            f2 xv;
            xv[0] = __uint_as_float(wd << 16);
            xv[1] = __uint_as_float(wd & 0xffff0000u);
            f2 a = xv * tl[i];
            f2 p;
            p[0] = __builtin_amdgcn_exp2f(a[0]);
            p[1] = __builtin_amdgcn_exp2f(a[1]);
            l[i] += p;
            s[i] = __builtin_elementwise_fma(p, xv, s[i]);
        }
    }
    bool has = end > beg;
    usv o;
#pragma unroll
    for (int i = 0; i < W; i++) {
        o[2 * i]     = f2bf(has ? s[i][0] / l[i][0] : 0.f);
        o[2 * i + 1] = f2bf(has ? s[i][1] / l[i][1] : 0.f);
    }
    *(usv*)(out + (size_t)node * C + cb) = o;
}

// ---------------- dual bf16 MFMA GEMM: C = A1*B1t^T + A2*B2t^T + bias ---------
// Tile 128x128, double-buffered LDS pipeline (T3 minimum 2-phase recipe):
// STAGE(step t+1 -> buf^1) issued BEFORE computing buf (staging latency hides
// under 64 MFMAs), ONE __syncthreads per K-step (drains vmcnt+lgkmcnt: next
// buf ready AND all reads of cur buf complete). Previous 2-barrier-per-step
// structure fully exposed the global_load_lds drain at 2.45 blocks/CU.
// XCD-affinity swizzle: all NTILES n-variants of one m-tile share bx%8.
// LN sum/sumsq fused into epilogue.
template <int K, int NT, int NTILES, int TN>
__global__ __launch_bounds__(256) void k_gemm_mfma(
    const unsigned short* __restrict__ A1, const unsigned short* __restrict__ B1t,
    const unsigned short* __restrict__ A2, const unsigned short* __restrict__ B2t,
    const float* __restrict__ bias, unsigned short* __restrict__ Co, int M,
    float* __restrict__ stat) {
    constexpr int NF = TN / 32;            // n-frags per wave (2 waves span TN)
    constexpr int H = K / 32;              // K-steps per phase
    constexpr int NSTEP = 2 * H;           // both phases, flat pipeline
    __shared__ short As[2][128 * 32];
    __shared__ short Bs[2][TN * 32];
    __shared__ float rs[256], rq[256];

    // swizzled decode: bx = x + 8*(n + NTILES*mh); m = mh*8 + x
    int bx = blockIdx.x;
    int xid = bx & 7, q = bx >> 3;
    int n = q % NTILES, mh = q / NTILES;
    int m = mh * 8 + xid;
    if (m * 128 >= MPAD) return;           // pad tiles: whole block exits
    int m0 = m * 128, n0 = n * TN;

    int t = threadIdx.x;
    int wv = t >> 6, lane = t & 63;
    int wm = wv & 1, wn = wv >> 1;
    int lm = lane & 15, quad = lane >> 4;
    int sr = t >> 2;
    int sc8 = (t & 3) * 8;

    f32x4 acc[4][NF] = {};

    auto stage = [&](int s, int buf) {
        const unsigned short* __restrict__ A  = (s < H) ? A1 : A2;
        const unsigned short* __restrict__ Bt = (s < H) ? B1t : B2t;
        int k0 = (s & (H - 1)) * 32;
#pragma unroll
        for (int it = 0; it < 2; it++)
            load_lds16(A + (size_t)(m0 + it * 64 + sr) * K + k0 + sc8,
                       (unsigned short*)&As[buf][it * 2048 + wv * 512]);
#pragma unroll
        for (int it = 0; it < TN / 64; it++)
            load_lds16(Bt + (size_t)(n0 + it * 64 + sr) * K + k0 + sc8,
                       (unsigned short*)&Bs[buf][it * 2048 + wv * 512]);
    };

    stage(0, 0);
    __syncthreads();                        // buf0 staged (vmcnt drained)
    for (int s = 0; s < NSTEP; s++) {
        int cur = s & 1;
        if (s + 1 < NSTEP) stage(s + 1, cur ^ 1);   // in flight during MFMA
        bf16x8 af[4], bfr[NF];
#pragma unroll
        for (int i = 0; i < 4; i++)
            af[i] = *(const bf16x8*)&As[cur][(wm * 64 + i * 16 + lm) * 32 + quad * 8];
#pragma unroll
        for (int j = 0; j < NF; j++)
            bfr[j] = *(const bf16x8*)&Bs[cur][(wn * (TN / 2) + j * 16 + lm) * 32 + quad * 8];
#pragma unroll
        for (int mi = 0; mi < 4; mi++)
#pragma unroll
            for (int nj = 0; nj < NF; nj++)
                acc[mi][nj] = __builtin_amdgcn_mfma_f32_16x16x32_bf16(
                    af[mi], bfr[nj], acc[mi][nj], 0, 0, 0);
        __syncthreads();                    // next buf landed; cur reads done
    }

    float sum = 0.f, ss = 0.f;
#pragma unroll
    for (int mi = 0; mi < 4; mi++) {
        int rb = m0 + wm * 64 + mi * 16 + quad * 4;
#pragma unroll
        for (int nj = 0; nj < NF; nj++) {
            int col = n0 + wn * (TN / 2) + nj * 16 + lm;
            float bb = bias[col];
#pragma unroll
            for (int rg = 0; rg < 4; rg++) {
                int row = rb + rg;
                if (row < M) {
                    float y = acc[mi][nj][rg] + bb;
                    Co[(size_t)row * NT + col] = f2bf(y);
                    sum += y; ss += y * y;
                }
            }
        }
    }
    rs[t] = sum; rq[t] = ss;
    __syncthreads();
    for (int o = 128; o > 0; o >>= 1) {
        if (t < o) { rs[t] += rs[t + o]; rq[t] += rq[t + o]; }
        __syncthreads();
    }
    if (t == 0) { atomicAdd(&stat[0], rs[0]); atomicAdd(&stat[1], rq[0]); }
}

// ---------------- graph-LN + ReLU, in-place bf16, vectorized x8 --------------
template <int C>
__global__ void k_ln_relu_b(unsigned short* __restrict__ h, int n,
                            const float* __restrict__ st,
                            const float* __restrict__ g, const float* __restrict__ b) {
    typedef unsigned short us8 __attribute__((ext_vector_type(8)));
    float mu = st[0] / (float)n;
    float var = st[1] / (float)n - mu * mu;
    var = var < 0.f ? 0.f : var;
    float inv = 1.0f / (sqrtf(var) + EPSV);
    int i8 = (blockIdx.x * blockDim.x + threadIdx.x) * 8;
    if (i8 >= n) return;
    int c = i8 & (C - 1);
    us8 v = *(const us8*)(h + i8);
    us8 o;
#pragma unroll
    for (int j = 0; j < 8; j++) {
        float y = (bf2f(v[j]) - mu) * inv * g[c + j] + b[c + j];
        o[j] = f2bf(fmaxf(y, 0.f));
    }
    *(us8*)(h + i8) = o;
}

// graph-LN + ReLU + column-sum only (layer 2; h2 not needed afterwards)
__global__ void k_ln_colsum(const unsigned short* __restrict__ h, int n,
                            const float* __restrict__ st,
                            const float* __restrict__ g, const float* __restrict__ b,
                            float* __restrict__ colsum) {
    float mu = st[0] / (float)n;
    float var = st[1] / (float)n - mu * mu;
    var = var < 0.f ? 0.f : var;
    float inv = 1.0f / (sqrtf(var) + EPSV);
    int t = threadIdx.x;
    float gv = g[t], bv = b[t];
    float local = 0.f;
    int stride = gridDim.x * blockDim.x;   // multiple of 256 -> channel == t always
    for (int i = blockIdx.x * blockDim.x + t; i < n; i += stride) {
        float y = (bf2f(h[i]) - mu) * inv * gv + bv;
        local += fmaxf(y, 0.f);
    }
    atomicAdd(&colsum[t], local);
}

// ---------------- head: mean-pool @ Wf + bf -> LN(64) -> relu ----------------
// split-K matvec: 256 threads = 4 k-groups x 64 out-cols (coalesced Wf reads),
// LDS-reduce the 4 partials, then wave-wide LN on 64 lanes.
__global__ void k_final(const float* __restrict__ colsum, const float* __restrict__ Wf,
                        const float* __restrict__ bf, const float* __restrict__ gx,
                        const float* __restrict__ bx, float* __restrict__ out) {
    __shared__ float p[256];
    __shared__ float red[4][64];
    int t = threadIdx.x;
    p[t] = colsum[t] * (1.0f / (float)NODES);
    __syncthreads();
    int kg = t >> 6, o = t & 63;
    float a = 0.f;
#pragma unroll
    for (int j = 0; j < 64; j++) {
        int c = kg + j * 4;
        a = fmaf(p[c], Wf[c * 64 + o], a);
    }
    red[kg][o] = a;
    __syncthreads();
    if (t < 64) {
        float acc = bf[t] + red[0][t] + red[1][t] + red[2][t] + red[3][t];
        float sum = acc;
        for (int w = 32; w > 0; w >>= 1) sum += __shfl_xor(sum, w);
        float mu = sum * (1.0f / 64.0f);
        float d = acc - mu;
        float vs = d * d;
        for (int w = 32; w > 0; w >>= 1) vs += __shfl_xor(vs, w);
        float var = vs * (1.0f / 64.0f);
        float y = d * rsqrtf(var + EPSV) * gx[t] + bx[t];
        out[t] = fmaxf(y, 0.f);
    }
}

extern "C" void kernel_launch(void* const* d_in, const int* in_sizes, int n_in,
                              void* d_out, int out_size, void* d_ws, size_t ws_size,
                              hipStream_t stream) {
    const float* x   = (const float*)d_in[0];
    const int*   ei  = (const int*)d_in[1];
    const float* t1  = (const float*)d_in[2];
    const float* Wl1 = (const float*)d_in[3];
    const float* bl1 = (const float*)d_in[4];
    const float* Wr1 = (const float*)d_in[5];
    const float* g1  = (const float*)d_in[6];
    const float* be1 = (const float*)d_in[7];
    const float* t2  = (const float*)d_in[8];
    const float* Wl2 = (const float*)d_in[9];
    const float* bl2 = (const float*)d_in[10];
    const float* Wr2 = (const float*)d_in[11];
    const float* g2  = (const float*)d_in[12];
    const float* be2 = (const float*)d_in[13];
    const float* Wf  = (const float*)d_in[14];
    const float* bf  = (const float*)d_in[15];
    const float* gx  = (const float*)d_in[16];
    const float* bx  = (const float*)d_in[17];
    float* out = (float*)d_out;

    char* ws = (char*)d_ws;
    size_t off = 0;
    auto alloc = [&](size_t bytes) { size_t o = off; off = (off + bytes + 511) & ~511ull; return o; };
    size_t o_counts = alloc((size_t)NODES * 4);
    size_t o_cursor = alloc((size_t)NODES * 4);
    size_t zero_bytes = off;                         // memset: counts+cursor only
    size_t o_acc    = alloc(4 * 4);
    size_t o_colsum = alloc(256 * 4);
    size_t o_offs = alloc((size_t)(NODES + 1) * 4);
    size_t o_csrc = alloc((size_t)EDGES * 4);
    size_t o_w1l  = alloc((size_t)512 * 256 * 2);
    size_t o_w1r  = alloc((size_t)512 * 256 * 2);
    size_t o_w2l  = alloc((size_t)256 * 512 * 2);
    size_t o_w2r  = alloc((size_t)256 * 512 * 2);
    size_t o_bufX = alloc((size_t)MPAD * 256 * 2);   // xb, later h2_pre (bf16)
    size_t o_agg  = alloc((size_t)MPAD * 512 * 2);   // agg1b / agg2b
    size_t o_h1   = alloc((size_t)(MPAD + 512) * 512 * 2); // h1 (+pad-tile slack)

    int*   counts = (int*)(ws + o_counts);
    int*   cursor = (int*)(ws + o_cursor);
    float* acc    = (float*)(ws + o_acc);      // [0,1]=L1 stats, [2,3]=L2 stats
    float* colsum = (float*)(ws + o_colsum);
    int*   offs   = (int*)(ws + o_offs);
    int*   csrc   = (int*)(ws + o_csrc);
    unsigned short* w1lt = (unsigned short*)(ws + o_w1l);
    unsigned short* w1rt = (unsigned short*)(ws + o_w1r);
    unsigned short* w2lt = (unsigned short*)(ws + o_w2l);
    unsigned short* w2rt = (unsigned short*)(ws + o_w2r);
    unsigned short* xb   = (unsigned short*)(ws + o_bufX);
    unsigned short* h2p  = (unsigned short*)(ws + o_bufX);  // reuse after xb dead
    unsigned short* aggb = (unsigned short*)(ws + o_agg);
    unsigned short* h1   = (unsigned short*)(ws + o_h1);

    const int* src = ei;
    const int* dst = ei + EDGES;

    hipMemsetAsync(ws, 0, zero_bytes, stream);

    // D1: fused prep (count + cast + transposes + zero acc/colsum)
    k_prep<<<PREP_TOTAL, 256, 0, stream>>>(dst, counts, x, xb,
                                           Wl1, Wr1, Wl2, Wr2,
                                           w1lt, w1rt, w2lt, w2rt,
                                           acc, colsum);
    // D2/D3: CSR scan (single dispatch) + scatter
    k_scan<<<1, 1024, 0, stream>>>(counts, offs);
    k_scatter<<<(EDGES + 255) / 256, 256, 0, stream>>>(src, dst, offs, cursor, csrc);

    // ----- layer 1 -----  (2 waves per node, 128 ch each)
    k_agg<256, 2, 8><<<(NODES * 2 + 3) / 4, 256, 0, stream>>>(xb, t1, offs, csrc, aggb);
    k_gemm_mfma<256, 512, 4, 128><<<8 * 4 * 20, 256, 0, stream>>>(
        aggb, w1lt, xb, w1rt, bl1, h1, NODES, acc);
    k_ln_relu_b<512><<<NODES * 512 / 8 / 256, 256, 0, stream>>>(h1, NODES * 512, acc, g1, be1);

    // ----- layer 2 -----  (2 waves per node, 256 ch each)
    k_agg<512, 2, 4><<<(NODES * 2 + 3) / 4, 256, 0, stream>>>(h1, t2, offs, csrc, aggb);
    k_gemm_mfma<512, 256, 2, 128><<<8 * 2 * 20, 256, 0, stream>>>(
        aggb, w2lt, h1, w2rt, bl2, h2p, NODES, acc + 2);

    // ----- LN2 + colsum, then head -----
    k_ln_colsum<<<1024, 256, 0, stream>>>(h2p, NODES * 256, acc + 2, g2, be2, colsum);
    k_final<<<1, 256, 0, stream>>>(colsum, Wf, bf, gx, bx, out);
}

// Round 4
// 326.383 us; speedup vs baseline: 1.0230x; 1.0230x over previous
//
#include <hip/hip_runtime.h>
#include <math.h>

#define NODES 20000
#define MPAD  20096          // NODES padded to multiple of 128 (GEMM M-tiles)
#define EDGES 320000
#define EPSV  1e-5f
#define LOG2E 1.4426950408889634f

// k_prep block ranges
#define PREP_CNT   1250                    // count: 1250*256 >= EDGES
#define PREP_CAST  5000                    // cast: NODES*256/4/256
#define PREP_TR    512                     // 4 matrices * 128 tiles
#define PREP_TOTAL (PREP_CNT + PREP_CAST + PREP_TR + 1)

typedef short bf16x8 __attribute__((ext_vector_type(8)));
typedef float f32x4  __attribute__((ext_vector_type(4)));
typedef float f2     __attribute__((ext_vector_type(2)));

__device__ __forceinline__ unsigned short f2bf(float f) {
    unsigned int u = __float_as_uint(f);
    u = (u + 0x7fffu + ((u >> 16) & 1u)) >> 16;
    return (unsigned short)u;
}
__device__ __forceinline__ float bf2f(unsigned short h) {
    return __uint_as_float(((unsigned int)h) << 16);
}

// async global->LDS, 16B per lane; lds dest = wave-uniform base + lane*16
__device__ __forceinline__ void load_lds16(const unsigned short* g, unsigned short* l) {
    __builtin_amdgcn_global_load_lds(
        (const __attribute__((address_space(1))) unsigned int*)g,
        (__attribute__((address_space(3))) unsigned int*)l, 16, 0, 0);
}

// ---------------- fused prep: edge-count + x cast + 4x weight transpose + zeros
__global__ void k_prep(const int* __restrict__ dst, int* __restrict__ counts,
                       const float* __restrict__ x, unsigned short* __restrict__ xb,
                       const float* __restrict__ Wl1, const float* __restrict__ Wr1,
                       const float* __restrict__ Wl2, const float* __restrict__ Wr2,
                       unsigned short* __restrict__ o1l, unsigned short* __restrict__ o1r,
                       unsigned short* __restrict__ o2l, unsigned short* __restrict__ o2r,
                       float* __restrict__ acc, float* __restrict__ colsum) {
    int b = blockIdx.x;
    int t = threadIdx.x;
    if (b < PREP_CNT) {
        int e = b * 256 + t;
        if (e < EDGES) atomicAdd(&counts[dst[e]], 1);
    } else if (b < PREP_CNT + PREP_CAST) {
        int i = ((b - PREP_CNT) * 256 + t) * 4;
        float4 v = *(const float4*)(x + i);
        xb[i + 0] = f2bf(v.x); xb[i + 1] = f2bf(v.y);
        xb[i + 2] = f2bf(v.z); xb[i + 3] = f2bf(v.w);
    } else if (b < PREP_CNT + PREP_CAST + PREP_TR) {
        __shared__ float tile[32][33];
        int zz = b - PREP_CNT - PREP_CAST;     // 0..511
        int z = zz >> 7;                        // matrix 0..3
        int idx = zz & 127;                     // tile within matrix
        const float* W = (z == 0) ? Wl1 : (z == 1) ? Wr1 : (z == 2) ? Wl2 : Wr2;
        unsigned short* Wt = (z == 0) ? o1l : (z == 1) ? o1r : (z == 2) ? o2l : o2r;
        int K = (z < 2) ? 256 : 512, N = (z < 2) ? 512 : 256;
        int nb = N / 32;
        int n0 = (idx % nb) * 32, k0 = (idx / nb) * 32;
        int tx = t & 31, ty = t >> 5;          // (32,8) layout
#pragma unroll
        for (int j = 0; j < 4; j++)
            tile[ty + j * 8][tx] = W[(size_t)(k0 + ty + j * 8) * N + n0 + tx];
        __syncthreads();
#pragma unroll
        for (int j = 0; j < 4; j++)
            Wt[(size_t)(n0 + ty + j * 8) * K + k0 + tx] = f2bf(tile[tx][ty + j * 8]);
    } else {
        if (t < 4) acc[t] = 0.f;
        colsum[t] = 0.f;
    }
}

// ---------------- single-dispatch CSR scan (1 block, 1024 thr, 20 nodes/thr) -
// Replaces the 3-dispatch hierarchical scan: same parallelism for this tiny
// array (80KB, L2-resident), minus two launches. 16 waves on one CU hide the
// 20-iteration per-thread walks.
#define SCAN_PN 20   // 1024*20 = 20480 >= NODES

__global__ __launch_bounds__(1024) void k_scan(const int* __restrict__ counts,
                                               int* __restrict__ offs) {
    __shared__ int sm[1024];
    int t = threadIdx.x;
    int i0 = t * SCAN_PN;
    int c[SCAN_PN];
    int s = 0;
#pragma unroll
    for (int j = 0; j < SCAN_PN; j++) {
        int i = i0 + j;
        c[j] = (i < NODES) ? counts[i] : 0;
        s += c[j];
    }
    sm[t] = s;
    __syncthreads();
    int v = s;
    for (int o = 1; o < 1024; o <<= 1) {
        int add = (t >= o) ? sm[t - o] : 0;
        __syncthreads();
        v += add;
        sm[t] = v;
        __syncthreads();
    }
    int run = v - s;
    if (t == 1023) offs[NODES] = v;
#pragma unroll
    for (int j = 0; j < SCAN_PN; j++) {
        int i = i0 + j;
        if (i < NODES) { offs[i] = run; run += c[j]; }
    }
}

__global__ void k_scatter(const int* __restrict__ src, const int* __restrict__ dst,
                          const int* __restrict__ offs, int* __restrict__ cursor,
                          int* __restrict__ csr_src) {
    int e = blockIdx.x * blockDim.x + threadIdx.x;
    if (e < EDGES) {
        int d = dst[e];
        int pos = atomicAdd(&cursor[d], 1);
        csr_src[offs[d] + pos] = src[e];
    }
}

// ------- per-channel softmax aggregation, un-stabilized (inputs bounded) -----
// S waves per node (interleaved waveg%S — measured fastest agg variant, r10).
// Wave-uniform CSR walk via readfirstlane: csr[k] -> s_load; vector pipe:
// loop-invariant-offset gather + packed-f32 exp2/fma.
// Measured floor ~44.5us (layer 2): 11 structural variants land 44-50us
// (incl. XCD-pinned channel slicing: fetch 133->60MB but time +2us — the
// kernel is issue/latency-bound, NOT fetch-bound; keep this config).
template <int C, int S, int UNR>
__global__ void k_agg(const unsigned short* __restrict__ xb, const float* __restrict__ tt,
                      const int* __restrict__ offs, const int* __restrict__ csr,
                      unsigned short* __restrict__ out) {
    constexpr int CS  = C / S;
    constexpr int VPL = CS / 64;
    constexpr int W   = VPL / 2;
    typedef unsigned int uv __attribute__((ext_vector_type(W)));
    typedef unsigned short usv __attribute__((ext_vector_type(VPL)));
    int waveg = (int)((blockIdx.x * (unsigned)blockDim.x + threadIdx.x) >> 6);
    int lane = threadIdx.x & 63;
    int node = waveg / S;
    int slice = waveg % S;
    if (node >= NODES) return;
    int beg = __builtin_amdgcn_readfirstlane(offs[node]);
    int end = __builtin_amdgcn_readfirstlane(offs[node + 1]);
    int cb = slice * CS + lane * VPL;
    const unsigned short* __restrict__ xcb = xb + cb;
    f2 tl[W], l[W], s[W];
#pragma unroll
    for (int i = 0; i < W; i++) {
        tl[i][0] = tt[cb + 2 * i] * LOG2E;
        tl[i][1] = tt[cb + 2 * i + 1] * LOG2E;
        l[i][0] = 0.f; l[i][1] = 0.f;
        s[i][0] = 0.f; s[i][1] = 0.f;
    }
    int k = beg;
    for (; k + UNR <= end; k += UNR) {
        uv v[UNR];
#pragma unroll
        for (int u = 0; u < UNR; u++) {
            int sn = csr[k + u];                     // uniform -> s_load
            v[u] = *(const uv*)(xcb + (size_t)sn * C);
        }
#pragma unroll
        for (int u = 0; u < UNR; u++)
#pragma unroll
            for (int i = 0; i < W; i++) {
                unsigned wd = v[u][i];
                f2 xv;
                xv[0] = __uint_as_float(wd << 16);
                xv[1] = __uint_as_float(wd & 0xffff0000u);
                f2 a = xv * tl[i];
                f2 p;
                p[0] = __builtin_amdgcn_exp2f(a[0]);
                p[1] = __builtin_amdgcn_exp2f(a[1]);
                l[i] += p;
                s[i] = __builtin_elementwise_fma(p, xv, s[i]);
            }
    }
    for (; k < end; k++) {
        int sn = csr[k];
        uv vv = *(const uv*)(xcb + (size_t)sn * C);
#pragma unroll
        for (int i = 0; i < W; i++) {
            unsigned wd = vv[i];
            f2 xv;
            xv[0] = __uint_as_float(wd << 16);
            xv[1] = __uint_as_float(wd & 0xffff0000u);
            f2 a = xv * tl[i];
            f2 p;
            p[0] = __builtin_amdgcn_exp2f(a[0]);
            p[1] = __builtin_amdgcn_exp2f(a[1]);
            l[i] += p;
            s[i] = __builtin_elementwise_fma(p, xv, s[i]);
        }
    }
    bool has = end > beg;
    usv o;
#pragma unroll
    for (int i = 0; i < W; i++) {
        o[2 * i]     = f2bf(has ? s[i][0] / l[i][0] : 0.f);
        o[2 * i + 1] = f2bf(has ? s[i][1] / l[i][1] : 0.f);
    }
    *(usv*)(out + (size_t)node * C + cb) = o;
}

// ---------------- dual bf16 MFMA GEMM: C = A1*B1t^T + A2*B2t^T + bias ---------
// Tile 128x128, single-buffer 2-barrier K-loop (round-2 proven structure;
// the r3 double-buffered variant REGRESSED ~7us/gemm: runtime-indexed LDS
// pipeline + 2x LDS beat the ~160cy of MFMA cover it bought).
// XCD-affinity swizzle: all NTILES n-variants of one m-tile share bx%8.
// LN sum/sumsq fused into epilogue (wave shfl-reduce, 1 barrier).
template <int K, int NT, int NTILES, int TN>
__global__ __launch_bounds__(256) void k_gemm_mfma(
    const unsigned short* __restrict__ A1, const unsigned short* __restrict__ B1t,
    const unsigned short* __restrict__ A2, const unsigned short* __restrict__ B2t,
    const float* __restrict__ bias, unsigned short* __restrict__ Co, int M,
    float* __restrict__ stat) {
    constexpr int NF = TN / 32;            // n-frags per wave (2 waves span TN)
    __shared__ short As[128 * 32];
    __shared__ short Bs[TN * 32];
    __shared__ float rs[8], rq[8];

    // swizzled decode: bx = x + 8*(n + NTILES*mh); m = mh*8 + x
    int bx = blockIdx.x;
    int xid = bx & 7, q = bx >> 3;
    int n = q % NTILES, mh = q / NTILES;
    int m = mh * 8 + xid;
    if (m * 128 >= MPAD) return;           // pad tiles: whole block exits
    int m0 = m * 128, n0 = n * TN;

    int t = threadIdx.x;
    int wv = t >> 6, lane = t & 63;
    int wm = wv & 1, wn = wv >> 1;
    int lm = lane & 15, quad = lane >> 4;
    int sr = t >> 2;
    int sc8 = (t & 3) * 8;

    f32x4 acc[4][NF] = {};

    for (int ph = 0; ph < 2; ph++) {
        const unsigned short* __restrict__ A  = ph ? A2 : A1;
        const unsigned short* __restrict__ Bt = ph ? B2t : B1t;
        for (int k0 = 0; k0 < K; k0 += 32) {
#pragma unroll
            for (int it = 0; it < 2; it++)
                load_lds16(A + (size_t)(m0 + it * 64 + sr) * K + k0 + sc8,
                           (unsigned short*)&As[it * 2048 + wv * 512]);
#pragma unroll
            for (int it = 0; it < TN / 64; it++)
                load_lds16(Bt + (size_t)(n0 + it * 64 + sr) * K + k0 + sc8,
                           (unsigned short*)&Bs[it * 2048 + wv * 512]);
            __syncthreads();
            bf16x8 af[4], bfr[NF];
#pragma unroll
            for (int i = 0; i < 4; i++)
                af[i] = *(const bf16x8*)&As[(wm * 64 + i * 16 + lm) * 32 + quad * 8];
#pragma unroll
            for (int j = 0; j < NF; j++)
                bfr[j] = *(const bf16x8*)&Bs[(wn * (TN / 2) + j * 16 + lm) * 32 + quad * 8];
#pragma unroll
            for (int mi = 0; mi < 4; mi++)
#pragma unroll
                for (int nj = 0; nj < NF; nj++)
                    acc[mi][nj] = __builtin_amdgcn_mfma_f32_16x16x32_bf16(
                        af[mi], bfr[nj], acc[mi][nj], 0, 0, 0);
            __syncthreads();
        }
    }

    float sum = 0.f, ss = 0.f;
#pragma unroll
    for (int mi = 0; mi < 4; mi++) {
        int rb = m0 + wm * 64 + mi * 16 + quad * 4;
#pragma unroll
        for (int nj = 0; nj < NF; nj++) {
            int col = n0 + wn * (TN / 2) + nj * 16 + lm;
            float bb = bias[col];
#pragma unroll
            for (int rg = 0; rg < 4; rg++) {
                int row = rb + rg;
                if (row < M) {
                    float y = acc[mi][nj][rg] + bb;
                    Co[(size_t)row * NT + col] = f2bf(y);
                    sum += y; ss += y * y;
                }
            }
        }
    }
    // wave shfl-reduce, then 1 barrier + single atomic pair per block
#pragma unroll
    for (int o = 32; o > 0; o >>= 1) {
        sum += __shfl_xor(sum, o);
        ss  += __shfl_xor(ss, o);
    }
    if (lane == 0) { rs[wv] = sum; rq[wv] = ss; }
    __syncthreads();
    if (t == 0) {
        float a0 = 0.f, a1 = 0.f;
#pragma unroll
        for (int i = 0; i < 4; i++) { a0 += rs[i] + rs[i + 4]; a1 += rq[i] + rq[i + 4]; }
        atomicAdd(&stat[0], a0); atomicAdd(&stat[1], a1);
    }
}

// ---------------- graph-LN + ReLU, in-place bf16, vectorized x8 --------------
template <int C>
__global__ void k_ln_relu_b(unsigned short* __restrict__ h, int n,
                            const float* __restrict__ st,
                            const float* __restrict__ g, const float* __restrict__ b) {
    typedef unsigned short us8 __attribute__((ext_vector_type(8)));
    float mu = st[0] / (float)n;
    float var = st[1] / (float)n - mu * mu;
    var = var < 0.f ? 0.f : var;
    float inv = 1.0f / (sqrtf(var) + EPSV);
    int i8 = (blockIdx.x * blockDim.x + threadIdx.x) * 8;
    if (i8 >= n) return;
    int c = i8 & (C - 1);
    us8 v = *(const us8*)(h + i8);
    us8 o;
#pragma unroll
    for (int j = 0; j < 8; j++) {
        float y = (bf2f(v[j]) - mu) * inv * g[c + j] + b[c + j];
        o[j] = f2bf(fmaxf(y, 0.f));
    }
    *(us8*)(h + i8) = o;
}

// graph-LN + ReLU + column-sum only (layer 2; h2 not needed afterwards)
__global__ void k_ln_colsum(const unsigned short* __restrict__ h, int n,
                            const float* __restrict__ st,
                            const float* __restrict__ g, const float* __restrict__ b,
                            float* __restrict__ colsum) {
    float mu = st[0] / (float)n;
    float var = st[1] / (float)n - mu * mu;
    var = var < 0.f ? 0.f : var;
    float inv = 1.0f / (sqrtf(var) + EPSV);
    int t = threadIdx.x;
    float gv = g[t], bv = b[t];
    float local = 0.f;
    int stride = gridDim.x * blockDim.x;   // multiple of 256 -> channel == t always
    for (int i = blockIdx.x * blockDim.x + t; i < n; i += stride) {
        float y = (bf2f(h[i]) - mu) * inv * gv + bv;
        local += fmaxf(y, 0.f);
    }
    atomicAdd(&colsum[t], local);
}

// ---------------- head: mean-pool @ Wf + bf -> LN(64) -> relu ----------------
// split-K matvec: 256 threads = 4 k-groups x 64 out-cols (coalesced Wf reads),
// LDS-reduce the 4 partials, then wave-wide LN on 64 lanes.
__global__ void k_final(const float* __restrict__ colsum, const float* __restrict__ Wf,
                        const float* __restrict__ bf, const float* __restrict__ gx,
                        const float* __restrict__ bx, float* __restrict__ out) {
    __shared__ float p[256];
    __shared__ float red[4][64];
    int t = threadIdx.x;
    p[t] = colsum[t] * (1.0f / (float)NODES);
    __syncthreads();
    int kg = t >> 6, o = t & 63;
    float a = 0.f;
#pragma unroll
    for (int j = 0; j < 64; j++) {
        int c = kg + j * 4;
        a = fmaf(p[c], Wf[c * 64 + o], a);
    }
    red[kg][o] = a;
    __syncthreads();
    if (t < 64) {
        float acc = bf[t] + red[0][t] + red[1][t] + red[2][t] + red[3][t];
        float sum = acc;
        for (int w = 32; w > 0; w >>= 1) sum += __shfl_xor(sum, w);
        float mu = sum * (1.0f / 64.0f);
        float d = acc - mu;
        float vs = d * d;
        for (int w = 32; w > 0; w >>= 1) vs += __shfl_xor(vs, w);
        float var = vs * (1.0f / 64.0f);
        float y = d * rsqrtf(var + EPSV) * gx[t] + bx[t];
        out[t] = fmaxf(y, 0.f);
    }
}

extern "C" void kernel_launch(void* const* d_in, const int* in_sizes, int n_in,
                              void* d_out, int out_size, void* d_ws, size_t ws_size,
                              hipStream_t stream) {
    const float* x   = (const float*)d_in[0];
    const int*   ei  = (const int*)d_in[1];
    const float* t1  = (const float*)d_in[2];
    const float* Wl1 = (const float*)d_in[3];
    const float* bl1 = (const float*)d_in[4];
    const float* Wr1 = (const float*)d_in[5];
    const float* g1  = (const float*)d_in[6];
    const float* be1 = (const float*)d_in[7];
    const float* t2  = (const float*)d_in[8];
    const float* Wl2 = (const float*)d_in[9];
    const float* bl2 = (const float*)d_in[10];
    const float* Wr2 = (const float*)d_in[11];
    const float* g2  = (const float*)d_in[12];
    const float* be2 = (const float*)d_in[13];
    const float* Wf  = (const float*)d_in[14];
    const float* bf  = (const float*)d_in[15];
    const float* gx  = (const float*)d_in[16];
    const float* bx  = (const float*)d_in[17];
    float* out = (float*)d_out;

    char* ws = (char*)d_ws;
    size_t off = 0;
    auto alloc = [&](size_t bytes) { size_t o = off; off = (off + bytes + 511) & ~511ull; return o; };
    size_t o_counts = alloc((size_t)NODES * 4);
    size_t o_cursor = alloc((size_t)NODES * 4);
    size_t zero_bytes = off;                         // memset: counts+cursor only
    size_t o_acc    = alloc(4 * 4);
    size_t o_colsum = alloc(256 * 4);
    size_t o_offs = alloc((size_t)(NODES + 1) * 4);
    size_t o_csrc = alloc((size_t)EDGES * 4);
    size_t o_w1l  = alloc((size_t)512 * 256 * 2);
    size_t o_w1r  = alloc((size_t)512 * 256 * 2);
    size_t o_w2l  = alloc((size_t)256 * 512 * 2);
    size_t o_w2r  = alloc((size_t)256 * 512 * 2);
    size_t o_bufX = alloc((size_t)MPAD * 256 * 2);   // xb, later h2_pre (bf16)
    size_t o_agg  = alloc((size_t)MPAD * 512 * 2);   // agg1b / agg2b
    size_t o_h1   = alloc((size_t)(MPAD + 512) * 512 * 2); // h1 (+pad-tile slack)

    int*   counts = (int*)(ws + o_counts);
    int*   cursor = (int*)(ws + o_cursor);
    float* acc    = (float*)(ws + o_acc);      // [0,1]=L1 stats, [2,3]=L2 stats
    float* colsum = (float*)(ws + o_colsum);
    int*   offs   = (int*)(ws + o_offs);
    int*   csrc   = (int*)(ws + o_csrc);
    unsigned short* w1lt = (unsigned short*)(ws + o_w1l);
    unsigned short* w1rt = (unsigned short*)(ws + o_w1r);
    unsigned short* w2lt = (unsigned short*)(ws + o_w2l);
    unsigned short* w2rt = (unsigned short*)(ws + o_w2r);
    unsigned short* xb   = (unsigned short*)(ws + o_bufX);
    unsigned short* h2p  = (unsigned short*)(ws + o_bufX);  // reuse after xb dead
    unsigned short* aggb = (unsigned short*)(ws + o_agg);
    unsigned short* h1   = (unsigned short*)(ws + o_h1);

    const int* src = ei;
    const int* dst = ei + EDGES;

    hipMemsetAsync(ws, 0, zero_bytes, stream);

    // D1: fused prep (count + cast + transposes + zero acc/colsum)
    k_prep<<<PREP_TOTAL, 256, 0, stream>>>(dst, counts, x, xb,
                                           Wl1, Wr1, Wl2, Wr2,
                                           w1lt, w1rt, w2lt, w2rt,
                                           acc, colsum);
    // D2/D3: CSR scan (single dispatch) + scatter
    k_scan<<<1, 1024, 0, stream>>>(counts, offs);
    k_scatter<<<(EDGES + 255) / 256, 256, 0, stream>>>(src, dst, offs, cursor, csrc);

    // ----- layer 1 -----  (2 waves per node, 128 ch each)
    k_agg<256, 2, 8><<<(NODES * 2 + 3) / 4, 256, 0, stream>>>(xb, t1, offs, csrc, aggb);
    k_gemm_mfma<256, 512, 4, 128><<<8 * 4 * 20, 256, 0, stream>>>(
        aggb, w1lt, xb, w1rt, bl1, h1, NODES, acc);
    k_ln_relu_b<512><<<NODES * 512 / 8 / 256, 256, 0, stream>>>(h1, NODES * 512, acc, g1, be1);

    // ----- layer 2 -----  (2 waves per node, 256 ch each)
    k_agg<512, 2, 4><<<(NODES * 2 + 3) / 4, 256, 0, stream>>>(h1, t2, offs, csrc, aggb);
    k_gemm_mfma<512, 256, 2, 128><<<8 * 2 * 20, 256, 0, stream>>>(
        aggb, w2lt, h1, w2rt, bl2, h2p, NODES, acc + 2);

    // ----- LN2 + colsum, then head -----
    k_ln_colsum<<<1024, 256, 0, stream>>>(h2p, NODES * 256, acc + 2, g2, be2, colsum);
    k_final<<<1, 256, 0, stream>>>(colsum, Wf, bf, gx, bx, out);
}

// Round 5
// 321.216 us; speedup vs baseline: 1.0394x; 1.0161x over previous
//
#include <hip/hip_runtime.h>
#include <math.h>

#define NODES 20000
#define MPAD  20096          // NODES padded to multiple of 128 (GEMM M-tiles)
#define EDGES 320000
#define EPSV  1e-5f
#define LOG2E 1.4426950408889634f

// k_prep block ranges
#define PREP_CNT   1250                    // count: 1250*256 >= EDGES
#define PREP_CAST  5000                    // cast: NODES*256/4/256
#define PREP_TR    512                     // 4 matrices * 128 tiles
#define PREP_TOTAL (PREP_CNT + PREP_CAST + PREP_TR + 1)

typedef short bf16x8 __attribute__((ext_vector_type(8)));
typedef float f32x4  __attribute__((ext_vector_type(4)));
typedef float f2     __attribute__((ext_vector_type(2)));

__device__ __forceinline__ unsigned short f2bf(float f) {
    unsigned int u = __float_as_uint(f);
    u = (u + 0x7fffu + ((u >> 16) & 1u)) >> 16;
    return (unsigned short)u;
}
__device__ __forceinline__ float bf2f(unsigned short h) {
    return __uint_as_float(((unsigned int)h) << 16);
}

// async global->LDS, 16B per lane; lds dest = wave-uniform base + lane*16
__device__ __forceinline__ void load_lds16(const unsigned short* g, unsigned short* l) {
    __builtin_amdgcn_global_load_lds(
        (const __attribute__((address_space(1))) unsigned int*)g,
        (__attribute__((address_space(3))) unsigned int*)l, 16, 0, 0);
}

// ---------------- fused prep: edge-count + x cast + 4x weight transpose + zeros
__global__ void k_prep(const int* __restrict__ dst, int* __restrict__ counts,
                       const float* __restrict__ x, unsigned short* __restrict__ xb,
                       const float* __restrict__ Wl1, const float* __restrict__ Wr1,
                       const float* __restrict__ Wl2, const float* __restrict__ Wr2,
                       unsigned short* __restrict__ o1l, unsigned short* __restrict__ o1r,
                       unsigned short* __restrict__ o2l, unsigned short* __restrict__ o2r,
                       float* __restrict__ acc, float* __restrict__ colsum) {
    int b = blockIdx.x;
    int t = threadIdx.x;
    if (b < PREP_CNT) {
        int e = b * 256 + t;
        if (e < EDGES) atomicAdd(&counts[dst[e]], 1);
    } else if (b < PREP_CNT + PREP_CAST) {
        int i = ((b - PREP_CNT) * 256 + t) * 4;
        float4 v = *(const float4*)(x + i);
        xb[i + 0] = f2bf(v.x); xb[i + 1] = f2bf(v.y);
        xb[i + 2] = f2bf(v.z); xb[i + 3] = f2bf(v.w);
    } else if (b < PREP_CNT + PREP_CAST + PREP_TR) {
        __shared__ float tile[32][33];
        int zz = b - PREP_CNT - PREP_CAST;     // 0..511
        int z = zz >> 7;                        // matrix 0..3
        int idx = zz & 127;                     // tile within matrix
        const float* W = (z == 0) ? Wl1 : (z == 1) ? Wr1 : (z == 2) ? Wl2 : Wr2;
        unsigned short* Wt = (z == 0) ? o1l : (z == 1) ? o1r : (z == 2) ? o2l : o2r;
        int K = (z < 2) ? 256 : 512, N = (z < 2) ? 512 : 256;
        int nb = N / 32;
        int n0 = (idx % nb) * 32, k0 = (idx / nb) * 32;
        int tx = t & 31, ty = t >> 5;          // (32,8) layout
#pragma unroll
        for (int j = 0; j < 4; j++)
            tile[ty + j * 8][tx] = W[(size_t)(k0 + ty + j * 8) * N + n0 + tx];
        __syncthreads();
#pragma unroll
        for (int j = 0; j < 4; j++)
            Wt[(size_t)(n0 + ty + j * 8) * K + k0 + tx] = f2bf(tile[tx][ty + j * 8]);
    } else {
        if (t < 4) acc[t] = 0.f;
        colsum[t] = 0.f;
    }
}

// ---------------- parallel CSR scan (3 small dispatches) + scatter ----------
// Measured fastest scan variant (r2: 318.4us wall). The single-1024-thread-
// block variant (r3/r4) is +8us: counts[t*20+j] loads are 80B-strided
// (uncoalesced) and everything serializes on one CU.
#define SCAN_B 32

__global__ void k_scan1(const int* __restrict__ counts, int* __restrict__ bsum) {
    __shared__ int sm[256];
    int t = threadIdx.x, b = blockIdx.x;
    int i0 = (b * 256 + t) * 3;
    int s = 0;
#pragma unroll
    for (int j = 0; j < 3; j++) { int i = i0 + j; if (i < NODES) s += counts[i]; }
    sm[t] = s;
    __syncthreads();
    int v = s;
#pragma unroll
    for (int o = 1; o < 256; o <<= 1) {
        int add = (t >= o) ? sm[t - o] : 0;
        __syncthreads();
        v += add;
        sm[t] = v;
        __syncthreads();
    }
    if (t == 255) bsum[b] = v;
}

// 1 wave: scan the 32 block sums -> exclusive bases; write offs[NODES]=total
__global__ void k_scan2(int* __restrict__ bsum, int* __restrict__ offs) {
    int t = threadIdx.x;                     // 64 threads = 1 wave
    int v = (t < SCAN_B) ? bsum[t] : 0;
    int x = v;
#pragma unroll
    for (int o = 1; o < 64; o <<= 1) {
        int y = __shfl_up(x, o);
        if (t >= o) x += y;
    }
    if (t < SCAN_B) bsum[t] = x - v;         // exclusive base
    if (t == SCAN_B - 1) offs[NODES] = x;    // grand total
}

__global__ void k_scan3(const int* __restrict__ counts, const int* __restrict__ bsum,
                        int* __restrict__ offs) {
    __shared__ int sm[256];
    int t = threadIdx.x, b = blockIdx.x;
    int i0 = (b * 256 + t) * 3;
    int c[3]; int s = 0;
#pragma unroll
    for (int j = 0; j < 3; j++) {
        int i = i0 + j;
        c[j] = (i < NODES) ? counts[i] : 0;
        s += c[j];
    }
    sm[t] = s;
    __syncthreads();
    int v = s;
#pragma unroll
    for (int o = 1; o < 256; o <<= 1) {
        int add = (t >= o) ? sm[t - o] : 0;
        __syncthreads();
        v += add;
        sm[t] = v;
        __syncthreads();
    }
    int run = bsum[b] + (v - s);             // block base + thread-exclusive
#pragma unroll
    for (int j = 0; j < 3; j++) {
        int i = i0 + j;
        if (i < NODES) { offs[i] = run; run += c[j]; }
    }
}

__global__ void k_scatter(const int* __restrict__ src, const int* __restrict__ dst,
                          const int* __restrict__ offs, int* __restrict__ cursor,
                          int* __restrict__ csr_src) {
    int e = blockIdx.x * blockDim.x + threadIdx.x;
    if (e < EDGES) {
        int d = dst[e];
        int pos = atomicAdd(&cursor[d], 1);
        csr_src[offs[d] + pos] = src[e];
    }
}

// ------- per-channel softmax aggregation, un-stabilized (inputs bounded) -----
// S waves per node (interleaved waveg%S — measured fastest agg variant, r10).
// Wave-uniform CSR walk via readfirstlane: csr[k] -> s_load; vector pipe:
// loop-invariant-offset gather + packed-f32 exp2/fma.
// Measured floor ~44.5us (layer 2): 11 structural variants land 44-50us
// (incl. XCD-pinned channel slicing: fetch 133->60MB but time +2us — the
// kernel is issue/latency-bound, NOT fetch-bound; keep this config).
template <int C, int S, int UNR>
__global__ void k_agg(const unsigned short* __restrict__ xb, const float* __restrict__ tt,
                      const int* __restrict__ offs, const int* __restrict__ csr,
                      unsigned short* __restrict__ out) {
    constexpr int CS  = C / S;
    constexpr int VPL = CS / 64;
    constexpr int W   = VPL / 2;
    typedef unsigned int uv __attribute__((ext_vector_type(W)));
    typedef unsigned short usv __attribute__((ext_vector_type(VPL)));
    int waveg = (int)((blockIdx.x * (unsigned)blockDim.x + threadIdx.x) >> 6);
    int lane = threadIdx.x & 63;
    int node = waveg / S;
    int slice = waveg % S;
    if (node >= NODES) return;
    int beg = __builtin_amdgcn_readfirstlane(offs[node]);
    int end = __builtin_amdgcn_readfirstlane(offs[node + 1]);
    int cb = slice * CS + lane * VPL;
    const unsigned short* __restrict__ xcb = xb + cb;
    f2 tl[W], l[W], s[W];
#pragma unroll
    for (int i = 0; i < W; i++) {
        tl[i][0] = tt[cb + 2 * i] * LOG2E;
        tl[i][1] = tt[cb + 2 * i + 1] * LOG2E;
        l[i][0] = 0.f; l[i][1] = 0.f;
        s[i][0] = 0.f; s[i][1] = 0.f;
    }
    int k = beg;
    for (; k + UNR <= end; k += UNR) {
        uv v[UNR];
#pragma unroll
        for (int u = 0; u < UNR; u++) {
            int sn = csr[k + u];                     // uniform -> s_load
            v[u] = *(const uv*)(xcb + (size_t)sn * C);
        }
#pragma unroll
        for (int u = 0; u < UNR; u++)
#pragma unroll
            for (int i = 0; i < W; i++) {
                unsigned wd = v[u][i];
                f2 xv;
                xv[0] = __uint_as_float(wd << 16);
                xv[1] = __uint_as_float(wd & 0xffff0000u);
                f2 a = xv * tl[i];
                f2 p;
                p[0] = __builtin_amdgcn_exp2f(a[0]);
                p[1] = __builtin_amdgcn_exp2f(a[1]);
                l[i] += p;
                s[i] = __builtin_elementwise_fma(p, xv, s[i]);
            }
    }
    for (; k < end; k++) {
        int sn = csr[k];
        uv vv = *(const uv*)(xcb + (size_t)sn * C);
#pragma unroll
        for (int i = 0; i < W; i++) {
            unsigned wd = vv[i];
            f2 xv;
            xv[0] = __uint_as_float(wd << 16);
            xv[1] = __uint_as_float(wd & 0xffff0000u);
            f2 a = xv * tl[i];
            f2 p;
            p[0] = __builtin_amdgcn_exp2f(a[0]);
            p[1] = __builtin_amdgcn_exp2f(a[1]);
            l[i] += p;
            s[i] = __builtin_elementwise_fma(p, xv, s[i]);
        }
    }
    bool has = end > beg;
    usv o;
#pragma unroll
    for (int i = 0; i < W; i++) {
        o[2 * i]     = f2bf(has ? s[i][0] / l[i][0] : 0.f);
        o[2 * i + 1] = f2bf(has ? s[i][1] / l[i][1] : 0.f);
    }
    *(usv*)(out + (size_t)node * C + cb) = o;
}

// ---------------- dual bf16 MFMA GEMM: C = A1*B1t^T + A2*B2t^T + bias ---------
// Tile 128x128. Pair-step K-loop: TWO 32-wide K-sub-steps staged into two
// compile-time-indexed LDS halves per barrier pair -> barriers halve, 128
// MFMAs per vmcnt-drain instead of 64, while keeping the proven conflict-free
// BK=32 stride-64B layout per half and NO runtime LDS indexing (the r3
// runtime-indexed dbuf variant regressed +7.5us).
// XCD-affinity swizzle: all NTILES n-variants of one m-tile share bx%8.
// LN sum/sumsq fused into epilogue (wave shfl-reduce, 1 barrier).
template <int K, int NT, int NTILES, int TN>
__global__ __launch_bounds__(256) void k_gemm_mfma(
    const unsigned short* __restrict__ A1, const unsigned short* __restrict__ B1t,
    const unsigned short* __restrict__ A2, const unsigned short* __restrict__ B2t,
    const float* __restrict__ bias, unsigned short* __restrict__ Co, int M,
    float* __restrict__ stat) {
    constexpr int NF = TN / 32;            // n-frags per wave (2 waves span TN)
    __shared__ short As[2 * 128 * 32];
    __shared__ short Bs[2 * TN * 32];
    __shared__ float rs[8], rq[8];

    // swizzled decode: bx = x + 8*(n + NTILES*mh); m = mh*8 + x
    int bx = blockIdx.x;
    int xid = bx & 7, q = bx >> 3;
    int n = q % NTILES, mh = q / NTILES;
    int m = mh * 8 + xid;
    if (m * 128 >= MPAD) return;           // pad tiles: whole block exits
    int m0 = m * 128, n0 = n * TN;

    int t = threadIdx.x;
    int wv = t >> 6, lane = t & 63;
    int wm = wv & 1, wn = wv >> 1;
    int lm = lane & 15, quad = lane >> 4;
    int sr = t >> 2;
    int sc8 = (t & 3) * 8;

    f32x4 acc[4][NF] = {};

    for (int ph = 0; ph < 2; ph++) {
        const unsigned short* __restrict__ A  = ph ? A2 : A1;
        const unsigned short* __restrict__ Bt = ph ? B2t : B1t;
        for (int k0 = 0; k0 < K; k0 += 64) {
#pragma unroll
            for (int h = 0; h < 2; h++) {
#pragma unroll
                for (int it = 0; it < 2; it++)
                    load_lds16(A + (size_t)(m0 + it * 64 + sr) * K + k0 + h * 32 + sc8,
                               (unsigned short*)&As[h * 4096 + it * 2048 + wv * 512]);
#pragma unroll
                for (int it = 0; it < TN / 64; it++)
                    load_lds16(Bt + (size_t)(n0 + it * 64 + sr) * K + k0 + h * 32 + sc8,
                               (unsigned short*)&Bs[h * (TN * 32) + it * 2048 + wv * 512]);
            }
            __syncthreads();
#pragma unroll
            for (int h = 0; h < 2; h++) {
                bf16x8 af[4], bfr[NF];
#pragma unroll
                for (int i = 0; i < 4; i++)
                    af[i] = *(const bf16x8*)&As[h * 4096 + (wm * 64 + i * 16 + lm) * 32 + quad * 8];
#pragma unroll
                for (int j = 0; j < NF; j++)
                    bfr[j] = *(const bf16x8*)&Bs[h * (TN * 32) + (wn * (TN / 2) + j * 16 + lm) * 32 + quad * 8];
#pragma unroll
                for (int mi = 0; mi < 4; mi++)
#pragma unroll
                    for (int nj = 0; nj < NF; nj++)
                        acc[mi][nj] = __builtin_amdgcn_mfma_f32_16x16x32_bf16(
                            af[mi], bfr[nj], acc[mi][nj], 0, 0, 0);
            }
            __syncthreads();
        }
    }

    float sum = 0.f, ss = 0.f;
#pragma unroll
    for (int mi = 0; mi < 4; mi++) {
        int rb = m0 + wm * 64 + mi * 16 + quad * 4;
#pragma unroll
        for (int nj = 0; nj < NF; nj++) {
            int col = n0 + wn * (TN / 2) + nj * 16 + lm;
            float bb = bias[col];
#pragma unroll
            for (int rg = 0; rg < 4; rg++) {
                int row = rb + rg;
                if (row < M) {
                    float y = acc[mi][nj][rg] + bb;
                    Co[(size_t)row * NT + col] = f2bf(y);
                    sum += y; ss += y * y;
                }
            }
        }
    }
    // wave shfl-reduce, then 1 barrier + single atomic pair per block
#pragma unroll
    for (int o = 32; o > 0; o >>= 1) {
        sum += __shfl_xor(sum, o);
        ss  += __shfl_xor(ss, o);
    }
    if (lane == 0) { rs[wv] = sum; rq[wv] = ss; }
    __syncthreads();
    if (t == 0) {
        float a0 = 0.f, a1 = 0.f;
#pragma unroll
        for (int i = 0; i < 4; i++) { a0 += rs[i] + rs[i + 4]; a1 += rq[i] + rq[i + 4]; }
        atomicAdd(&stat[0], a0); atomicAdd(&stat[1], a1);
    }
}

// ---------------- graph-LN + ReLU, in-place bf16, vectorized x8 --------------
template <int C>
__global__ void k_ln_relu_b(unsigned short* __restrict__ h, int n,
                            const float* __restrict__ st,
                            const float* __restrict__ g, const float* __restrict__ b) {
    typedef unsigned short us8 __attribute__((ext_vector_type(8)));
    float mu = st[0] / (float)n;
    float var = st[1] / (float)n - mu * mu;
    var = var < 0.f ? 0.f : var;
    float inv = 1.0f / (sqrtf(var) + EPSV);
    int i8 = (blockIdx.x * blockDim.x + threadIdx.x) * 8;
    if (i8 >= n) return;
    int c = i8 & (C - 1);
    us8 v = *(const us8*)(h + i8);
    us8 o;
#pragma unroll
    for (int j = 0; j < 8; j++) {
        float y = (bf2f(v[j]) - mu) * inv * g[c + j] + b[c + j];
        o[j] = f2bf(fmaxf(y, 0.f));
    }
    *(us8*)(h + i8) = o;
}

// graph-LN + ReLU + column-sum only (layer 2; h2 not needed afterwards)
__global__ void k_ln_colsum(const unsigned short* __restrict__ h, int n,
                            const float* __restrict__ st,
                            const float* __restrict__ g, const float* __restrict__ b,
                            float* __restrict__ colsum) {
    float mu = st[0] / (float)n;
    float var = st[1] / (float)n - mu * mu;
    var = var < 0.f ? 0.f : var;
    float inv = 1.0f / (sqrtf(var) + EPSV);
    int t = threadIdx.x;
    float gv = g[t], bv = b[t];
    float local = 0.f;
    int stride = gridDim.x * blockDim.x;   // multiple of 256 -> channel == t always
    for (int i = blockIdx.x * blockDim.x + t; i < n; i += stride) {
        float y = (bf2f(h[i]) - mu) * inv * gv + bv;
        local += fmaxf(y, 0.f);
    }
    atomicAdd(&colsum[t], local);
}

// ---------------- head: mean-pool @ Wf + bf -> LN(64) -> relu ----------------
// split-K matvec: 256 threads = 4 k-groups x 64 out-cols (coalesced Wf reads),
// LDS-reduce the 4 partials, then wave-wide LN on 64 lanes.
__global__ void k_final(const float* __restrict__ colsum, const float* __restrict__ Wf,
                        const float* __restrict__ bf, const float* __restrict__ gx,
                        const float* __restrict__ bx, float* __restrict__ out) {
    __shared__ float p[256];
    __shared__ float red[4][64];
    int t = threadIdx.x;
    p[t] = colsum[t] * (1.0f / (float)NODES);
    __syncthreads();
    int kg = t >> 6, o = t & 63;
    float a = 0.f;
#pragma unroll
    for (int j = 0; j < 64; j++) {
        int c = kg + j * 4;
        a = fmaf(p[c], Wf[c * 64 + o], a);
    }
    red[kg][o] = a;
    __syncthreads();
    if (t < 64) {
        float acc = bf[t] + red[0][t] + red[1][t] + red[2][t] + red[3][t];
        float sum = acc;
        for (int w = 32; w > 0; w >>= 1) sum += __shfl_xor(sum, w);
        float mu = sum * (1.0f / 64.0f);
        float d = acc - mu;
        float vs = d * d;
        for (int w = 32; w > 0; w >>= 1) vs += __shfl_xor(vs, w);
        float var = vs * (1.0f / 64.0f);
        float y = d * rsqrtf(var + EPSV) * gx[t] + bx[t];
        out[t] = fmaxf(y, 0.f);
    }
}

extern "C" void kernel_launch(void* const* d_in, const int* in_sizes, int n_in,
                              void* d_out, int out_size, void* d_ws, size_t ws_size,
                              hipStream_t stream) {
    const float* x   = (const float*)d_in[0];
    const int*   ei  = (const int*)d_in[1];
    const float* t1  = (const float*)d_in[2];
    const float* Wl1 = (const float*)d_in[3];
    const float* bl1 = (const float*)d_in[4];
    const float* Wr1 = (const float*)d_in[5];
    const float* g1  = (const float*)d_in[6];
    const float* be1 = (const float*)d_in[7];
    const float* t2  = (const float*)d_in[8];
    const float* Wl2 = (const float*)d_in[9];
    const float* bl2 = (const float*)d_in[10];
    const float* Wr2 = (const float*)d_in[11];
    const float* g2  = (const float*)d_in[12];
    const float* be2 = (const float*)d_in[13];
    const float* Wf  = (const float*)d_in[14];
    const float* bf  = (const float*)d_in[15];
    const float* gx  = (const float*)d_in[16];
    const float* bx  = (const float*)d_in[17];
    float* out = (float*)d_out;

    char* ws = (char*)d_ws;
    size_t off = 0;
    auto alloc = [&](size_t bytes) { size_t o = off; off = (off + bytes + 511) & ~511ull; return o; };
    size_t o_counts = alloc((size_t)NODES * 4);
    size_t o_cursor = alloc((size_t)NODES * 4);
    size_t zero_bytes = off;                         // memset: counts+cursor only
    size_t o_acc    = alloc(4 * 4);
    size_t o_colsum = alloc(256 * 4);
    size_t o_bsum = alloc((size_t)SCAN_B * 4);
    size_t o_offs = alloc((size_t)(NODES + 1) * 4);
    size_t o_csrc = alloc((size_t)EDGES * 4);
    size_t o_w1l  = alloc((size_t)512 * 256 * 2);
    size_t o_w1r  = alloc((size_t)512 * 256 * 2);
    size_t o_w2l  = alloc((size_t)256 * 512 * 2);
    size_t o_w2r  = alloc((size_t)256 * 512 * 2);
    size_t o_bufX = alloc((size_t)MPAD * 256 * 2);   // xb, later h2_pre (bf16)
    size_t o_agg  = alloc((size_t)MPAD * 512 * 2);   // agg1b / agg2b
    size_t o_h1   = alloc((size_t)(MPAD + 512) * 512 * 2); // h1 (+pad-tile slack)

    int*   counts = (int*)(ws + o_counts);
    int*   cursor = (int*)(ws + o_cursor);
    float* acc    = (float*)(ws + o_acc);      // [0,1]=L1 stats, [2,3]=L2 stats
    float* colsum = (float*)(ws + o_colsum);
    int*   bsum   = (int*)(ws + o_bsum);
    int*   offs   = (int*)(ws + o_offs);
    int*   csrc   = (int*)(ws + o_csrc);
    unsigned short* w1lt = (unsigned short*)(ws + o_w1l);
    unsigned short* w1rt = (unsigned short*)(ws + o_w1r);
    unsigned short* w2lt = (unsigned short*)(ws + o_w2l);
    unsigned short* w2rt = (unsigned short*)(ws + o_w2r);
    unsigned short* xb   = (unsigned short*)(ws + o_bufX);
    unsigned short* h2p  = (unsigned short*)(ws + o_bufX);  // reuse after xb dead
    unsigned short* aggb = (unsigned short*)(ws + o_agg);
    unsigned short* h1   = (unsigned short*)(ws + o_h1);

    const int* src = ei;
    const int* dst = ei + EDGES;

    hipMemsetAsync(ws, 0, zero_bytes, stream);

    // D1: fused prep (count + cast + transposes + zero acc/colsum)
    k_prep<<<PREP_TOTAL, 256, 0, stream>>>(dst, counts, x, xb,
                                           Wl1, Wr1, Wl2, Wr2,
                                           w1lt, w1rt, w2lt, w2rt,
                                           acc, colsum);
    // D2-D4: parallel CSR scan, then scatter
    k_scan1<<<SCAN_B, 256, 0, stream>>>(counts, bsum);
    k_scan2<<<1, 64, 0, stream>>>(bsum, offs);
    k_scan3<<<SCAN_B, 256, 0, stream>>>(counts, bsum, offs);
    k_scatter<<<(EDGES + 255) / 256, 256, 0, stream>>>(src, dst, offs, cursor, csrc);

    // ----- layer 1 -----  (2 waves per node, 128 ch each)
    k_agg<256, 2, 8><<<(NODES * 2 + 3) / 4, 256, 0, stream>>>(xb, t1, offs, csrc, aggb);
    k_gemm_mfma<256, 512, 4, 128><<<8 * 4 * 20, 256, 0, stream>>>(
        aggb, w1lt, xb, w1rt, bl1, h1, NODES, acc);
    k_ln_relu_b<512><<<NODES * 512 / 8 / 256, 256, 0, stream>>>(h1, NODES * 512, acc, g1, be1);

    // ----- layer 2 -----  (2 waves per node, 256 ch each)
    k_agg<512, 2, 4><<<(NODES * 2 + 3) / 4, 256, 0, stream>>>(h1, t2, offs, csrc, aggb);
    k_gemm_mfma<512, 256, 2, 128><<<8 * 2 * 20, 256, 0, stream>>>(
        aggb, w2lt, h1, w2rt, bl2, h2p, NODES, acc + 2);

    // ----- LN2 + colsum, then head -----
    k_ln_colsum<<<1024, 256, 0, stream>>>(h2p, NODES * 256, acc + 2, g2, be2, colsum);
    k_final<<<1, 256, 0, stream>>>(colsum, Wf, bf, gx, bx, out);
}

// Round 6
// 320.838 us; speedup vs baseline: 1.0407x; 1.0012x over previous
//
#include <hip/hip_runtime.h>
#include <math.h>

#define NODES 20000
#define MPAD  20096          // NODES padded to multiple of 128 (GEMM M-tiles)
#define EDGES 320000
#define EPSV  1e-5f
#define LOG2E 1.4426950408889634f

// k_prep block ranges
#define PREP_CNT   1250                    // count: 1250*256 >= EDGES
#define PREP_CAST  5000                    // cast: NODES*256/4/256
#define PREP_TR    512                     // 4 matrices * 128 tiles
#define PREP_TOTAL (PREP_CNT + PREP_CAST + PREP_TR + 1)

typedef short bf16x8 __attribute__((ext_vector_type(8)));
typedef float f32x4  __attribute__((ext_vector_type(4)));
typedef float f2     __attribute__((ext_vector_type(2)));

__device__ __forceinline__ unsigned short f2bf(float f) {
    unsigned int u = __float_as_uint(f);
    u = (u + 0x7fffu + ((u >> 16) & 1u)) >> 16;
    return (unsigned short)u;
}
__device__ __forceinline__ float bf2f(unsigned short h) {
    return __uint_as_float(((unsigned int)h) << 16);
}

// async global->LDS, 16B per lane; lds dest = wave-uniform base + lane*16
__device__ __forceinline__ void load_lds16(const unsigned short* g, unsigned short* l) {
    __builtin_amdgcn_global_load_lds(
        (const __attribute__((address_space(1))) unsigned int*)g,
        (__attribute__((address_space(3))) unsigned int*)l, 16, 0, 0);
}

// ---------------- fused prep: edge-count + x cast + 4x weight transpose + zeros
__global__ void k_prep(const int* __restrict__ dst, int* __restrict__ counts,
                       const float* __restrict__ x, unsigned short* __restrict__ xb,
                       const float* __restrict__ Wl1, const float* __restrict__ Wr1,
                       const float* __restrict__ Wl2, const float* __restrict__ Wr2,
                       unsigned short* __restrict__ o1l, unsigned short* __restrict__ o1r,
                       unsigned short* __restrict__ o2l, unsigned short* __restrict__ o2r,
                       float* __restrict__ acc, float* __restrict__ colsum) {
    int b = blockIdx.x;
    int t = threadIdx.x;
    if (b < PREP_CNT) {
        int e = b * 256 + t;
        if (e < EDGES) atomicAdd(&counts[dst[e]], 1);
    } else if (b < PREP_CNT + PREP_CAST) {
        int i = ((b - PREP_CNT) * 256 + t) * 4;
        float4 v = *(const float4*)(x + i);
        xb[i + 0] = f2bf(v.x); xb[i + 1] = f2bf(v.y);
        xb[i + 2] = f2bf(v.z); xb[i + 3] = f2bf(v.w);
    } else if (b < PREP_CNT + PREP_CAST + PREP_TR) {
        __shared__ float tile[32][33];
        int zz = b - PREP_CNT - PREP_CAST;     // 0..511
        int z = zz >> 7;                        // matrix 0..3
        int idx = zz & 127;                     // tile within matrix
        const float* W = (z == 0) ? Wl1 : (z == 1) ? Wr1 : (z == 2) ? Wl2 : Wr2;
        unsigned short* Wt = (z == 0) ? o1l : (z == 1) ? o1r : (z == 2) ? o2l : o2r;
        int K = (z < 2) ? 256 : 512, N = (z < 2) ? 512 : 256;
        int nb = N / 32;
        int n0 = (idx % nb) * 32, k0 = (idx / nb) * 32;
        int tx = t & 31, ty = t >> 5;          // (32,8) layout
#pragma unroll
        for (int j = 0; j < 4; j++)
            tile[ty + j * 8][tx] = W[(size_t)(k0 + ty + j * 8) * N + n0 + tx];
        __syncthreads();
#pragma unroll
        for (int j = 0; j < 4; j++)
            Wt[(size_t)(n0 + ty + j * 8) * K + k0 + tx] = f2bf(tile[tx][ty + j * 8]);
    } else {
        if (t < 4) acc[t] = 0.f;
        colsum[t] = 0.f;
    }
}

// ---------------- parallel CSR scan (3 small dispatches) + scatter ----------
// Measured fastest scan variant (r2: 318.4us wall). The single-1024-thread-
// block variant (r3/r4) is +8us: counts[t*20+j] loads are 80B-strided
// (uncoalesced) and everything serializes on one CU.
#define SCAN_B 32

__global__ void k_scan1(const int* __restrict__ counts, int* __restrict__ bsum) {
    __shared__ int sm[256];
    int t = threadIdx.x, b = blockIdx.x;
    int i0 = (b * 256 + t) * 3;
    int s = 0;
#pragma unroll
    for (int j = 0; j < 3; j++) { int i = i0 + j; if (i < NODES) s += counts[i]; }
    sm[t] = s;
    __syncthreads();
    int v = s;
#pragma unroll
    for (int o = 1; o < 256; o <<= 1) {
        int add = (t >= o) ? sm[t - o] : 0;
        __syncthreads();
        v += add;
        sm[t] = v;
        __syncthreads();
    }
    if (t == 255) bsum[b] = v;
}

// 1 wave: scan the 32 block sums -> exclusive bases; write offs[NODES]=total
__global__ void k_scan2(int* __restrict__ bsum, int* __restrict__ offs) {
    int t = threadIdx.x;                     // 64 threads = 1 wave
    int v = (t < SCAN_B) ? bsum[t] : 0;
    int x = v;
#pragma unroll
    for (int o = 1; o < 64; o <<= 1) {
        int y = __shfl_up(x, o);
        if (t >= o) x += y;
    }
    if (t < SCAN_B) bsum[t] = x - v;         // exclusive base
    if (t == SCAN_B - 1) offs[NODES] = x;    // grand total
}

__global__ void k_scan3(const int* __restrict__ counts, const int* __restrict__ bsum,
                        int* __restrict__ offs) {
    __shared__ int sm[256];
    int t = threadIdx.x, b = blockIdx.x;
    int i0 = (b * 256 + t) * 3;
    int c[3]; int s = 0;
#pragma unroll
    for (int j = 0; j < 3; j++) {
        int i = i0 + j;
        c[j] = (i < NODES) ? counts[i] : 0;
        s += c[j];
    }
    sm[t] = s;
    __syncthreads();
    int v = s;
#pragma unroll
    for (int o = 1; o < 256; o <<= 1) {
        int add = (t >= o) ? sm[t - o] : 0;
        __syncthreads();
        v += add;
        sm[t] = v;
        __syncthreads();
    }
    int run = bsum[b] + (v - s);             // block base + thread-exclusive
#pragma unroll
    for (int j = 0; j < 3; j++) {
        int i = i0 + j;
        if (i < NODES) { offs[i] = run; run += c[j]; }
    }
}

__global__ void k_scatter(const int* __restrict__ src, const int* __restrict__ dst,
                          const int* __restrict__ offs, int* __restrict__ cursor,
                          int* __restrict__ csr_src) {
    int e = blockIdx.x * blockDim.x + threadIdx.x;
    if (e < EDGES) {
        int d = dst[e];
        int pos = atomicAdd(&cursor[d], 1);
        csr_src[offs[d] + pos] = src[e];
    }
}

// ------- per-channel softmax aggregation, un-stabilized (inputs bounded) -----
// S waves per node (interleaved waveg%S — measured fastest agg variant, r10).
// Wave-uniform CSR walk via readfirstlane: csr[k] -> s_load; vector pipe:
// loop-invariant-offset gather + packed-f32 exp2/fma.
// Measured floor ~44.5us (layer 2): 11 structural variants land 44-50us
// (incl. XCD-pinned channel slicing: fetch 133->60MB but time +2us — the
// kernel is issue/latency-bound, NOT fetch-bound; keep this config).
template <int C, int S, int UNR>
__global__ void k_agg(const unsigned short* __restrict__ xb, const float* __restrict__ tt,
                      const int* __restrict__ offs, const int* __restrict__ csr,
                      unsigned short* __restrict__ out) {
    constexpr int CS  = C / S;
    constexpr int VPL = CS / 64;
    constexpr int W   = VPL / 2;
    typedef unsigned int uv __attribute__((ext_vector_type(W)));
    typedef unsigned short usv __attribute__((ext_vector_type(VPL)));
    int waveg = (int)((blockIdx.x * (unsigned)blockDim.x + threadIdx.x) >> 6);
    int lane = threadIdx.x & 63;
    int node = waveg / S;
    int slice = waveg % S;
    if (node >= NODES) return;
    int beg = __builtin_amdgcn_readfirstlane(offs[node]);
    int end = __builtin_amdgcn_readfirstlane(offs[node + 1]);
    int cb = slice * CS + lane * VPL;
    const unsigned short* __restrict__ xcb = xb + cb;
    f2 tl[W], l[W], s[W];
#pragma unroll
    for (int i = 0; i < W; i++) {
        tl[i][0] = tt[cb + 2 * i] * LOG2E;
        tl[i][1] = tt[cb + 2 * i + 1] * LOG2E;
        l[i][0] = 0.f; l[i][1] = 0.f;
        s[i][0] = 0.f; s[i][1] = 0.f;
    }
    int k = beg;
    for (; k + UNR <= end; k += UNR) {
        uv v[UNR];
#pragma unroll
        for (int u = 0; u < UNR; u++) {
            int sn = csr[k + u];                     // uniform -> s_load
            v[u] = *(const uv*)(xcb + (size_t)sn * C);
        }
#pragma unroll
        for (int u = 0; u < UNR; u++)
#pragma unroll
            for (int i = 0; i < W; i++) {
                unsigned wd = v[u][i];
                f2 xv;
                xv[0] = __uint_as_float(wd << 16);
                xv[1] = __uint_as_float(wd & 0xffff0000u);
                f2 a = xv * tl[i];
                f2 p;
                p[0] = __builtin_amdgcn_exp2f(a[0]);
                p[1] = __builtin_amdgcn_exp2f(a[1]);
                l[i] += p;
                s[i] = __builtin_elementwise_fma(p, xv, s[i]);
            }
    }
    for (; k < end; k++) {
        int sn = csr[k];
        uv vv = *(const uv*)(xcb + (size_t)sn * C);
#pragma unroll
        for (int i = 0; i < W; i++) {
            unsigned wd = vv[i];
            f2 xv;
            xv[0] = __uint_as_float(wd << 16);
            xv[1] = __uint_as_float(wd & 0xffff0000u);
            f2 a = xv * tl[i];
            f2 p;
            p[0] = __builtin_amdgcn_exp2f(a[0]);
            p[1] = __builtin_amdgcn_exp2f(a[1]);
            l[i] += p;
            s[i] = __builtin_elementwise_fma(p, xv, s[i]);
        }
    }
    bool has = end > beg;
    usv o;
#pragma unroll
    for (int i = 0; i < W; i++) {
        o[2 * i]     = f2bf(has ? s[i][0] / l[i][0] : 0.f);
        o[2 * i + 1] = f2bf(has ? s[i][1] / l[i][1] : 0.f);
    }
    *(usv*)(out + (size_t)node * C + cb) = o;
}

// ---------------- dual bf16 MFMA GEMM: C = A1*B1t^T + A2*B2t^T + bias ---------
// Tile 128x128. SLAB staging: 4 x 32-wide K-chunks (128-wide slab) staged per
// barrier pair -> vmcnt(0) drains cut 4x (gemm1 16->4, gemm2 32->8). r5 PMC
// showed the old per-32-step structure at MfmaUtil 8.3% / occupancy 11% —
// pure latency exposure at every drain with only 2.5 blocks/CU TLP; r3/r5
// proved reshuffling barriers at the SAME drain count is neutral-to-negative.
// Per-chunk LDS layout and read addressing unchanged (row-major [128][32]
// per chunk). LDS 64KB -> 2 blocks/CU (neighbor streams while we compute).
// XCD-affinity swizzle: all NTILES n-variants of one m-tile share bx%8.
// LN sum/sumsq fused into epilogue (wave shfl-reduce, 1 barrier).
template <int K, int NT, int NTILES, int TN>
__global__ __launch_bounds__(256) void k_gemm_mfma(
    const unsigned short* __restrict__ A1, const unsigned short* __restrict__ B1t,
    const unsigned short* __restrict__ A2, const unsigned short* __restrict__ B2t,
    const float* __restrict__ bias, unsigned short* __restrict__ Co, int M,
    float* __restrict__ stat) {
    constexpr int NF = TN / 32;            // n-frags per wave (2 waves span TN)
    __shared__ short As[4 * 128 * 32];     // 4 k-chunks, [128][32] each
    __shared__ short Bs[4 * TN * 32];
    __shared__ float rs[8], rq[8];

    // swizzled decode: bx = x + 8*(n + NTILES*mh); m = mh*8 + x
    int bx = blockIdx.x;
    int xid = bx & 7, q = bx >> 3;
    int n = q % NTILES, mh = q / NTILES;
    int m = mh * 8 + xid;
    if (m * 128 >= MPAD) return;           // pad tiles: whole block exits
    int m0 = m * 128, n0 = n * TN;

    int t = threadIdx.x;
    int wv = t >> 6, lane = t & 63;
    int wm = wv & 1, wn = wv >> 1;
    int lm = lane & 15, quad = lane >> 4;
    int sr = t >> 2;
    int sc8 = (t & 3) * 8;

    f32x4 acc[4][NF] = {};

    for (int ph = 0; ph < 2; ph++) {
        const unsigned short* __restrict__ A  = ph ? A2 : A1;
        const unsigned short* __restrict__ Bt = ph ? B2t : B1t;
        for (int ks = 0; ks < K; ks += 128) {
#pragma unroll
            for (int c = 0; c < 4; c++) {
#pragma unroll
                for (int it = 0; it < 2; it++)
                    load_lds16(A + (size_t)(m0 + it * 64 + sr) * K + ks + c * 32 + sc8,
                               (unsigned short*)&As[c * 4096 + it * 2048 + wv * 512]);
#pragma unroll
                for (int it = 0; it < TN / 64; it++)
                    load_lds16(Bt + (size_t)(n0 + it * 64 + sr) * K + ks + c * 32 + sc8,
                               (unsigned short*)&Bs[c * (TN * 32) + it * 2048 + wv * 512]);
            }
            __syncthreads();               // ONE vmcnt drain per 128-wide slab
#pragma unroll
            for (int c = 0; c < 4; c++) {
                bf16x8 af[4], bfr[NF];
#pragma unroll
                for (int i = 0; i < 4; i++)
                    af[i] = *(const bf16x8*)&As[c * 4096 + (wm * 64 + i * 16 + lm) * 32 + quad * 8];
#pragma unroll
                for (int j = 0; j < NF; j++)
                    bfr[j] = *(const bf16x8*)&Bs[c * (TN * 32) + (wn * (TN / 2) + j * 16 + lm) * 32 + quad * 8];
#pragma unroll
                for (int mi = 0; mi < 4; mi++)
#pragma unroll
                    for (int nj = 0; nj < NF; nj++)
                        acc[mi][nj] = __builtin_amdgcn_mfma_f32_16x16x32_bf16(
                            af[mi], bfr[nj], acc[mi][nj], 0, 0, 0);
            }
            __syncthreads();
        }
    }

    float sum = 0.f, ss = 0.f;
#pragma unroll
    for (int mi = 0; mi < 4; mi++) {
        int rb = m0 + wm * 64 + mi * 16 + quad * 4;
#pragma unroll
        for (int nj = 0; nj < NF; nj++) {
            int col = n0 + wn * (TN / 2) + nj * 16 + lm;
            float bb = bias[col];
#pragma unroll
            for (int rg = 0; rg < 4; rg++) {
                int row = rb + rg;
                if (row < M) {
                    float y = acc[mi][nj][rg] + bb;
                    Co[(size_t)row * NT + col] = f2bf(y);
                    sum += y; ss += y * y;
                }
            }
        }
    }
    // wave shfl-reduce, then 1 barrier + single atomic pair per block
#pragma unroll
    for (int o = 32; o > 0; o >>= 1) {
        sum += __shfl_xor(sum, o);
        ss  += __shfl_xor(ss, o);
    }
    if (lane == 0) { rs[wv] = sum; rq[wv] = ss; }
    __syncthreads();
    if (t == 0) {
        float a0 = 0.f, a1 = 0.f;
#pragma unroll
        for (int i = 0; i < 4; i++) { a0 += rs[i] + rs[i + 4]; a1 += rq[i] + rq[i + 4]; }
        atomicAdd(&stat[0], a0); atomicAdd(&stat[1], a1);
    }
}

// ---------------- graph-LN + ReLU, in-place bf16, vectorized x8 --------------
template <int C>
__global__ void k_ln_relu_b(unsigned short* __restrict__ h, int n,
                            const float* __restrict__ st,
                            const float* __restrict__ g, const float* __restrict__ b) {
    typedef unsigned short us8 __attribute__((ext_vector_type(8)));
    float mu = st[0] / (float)n;
    float var = st[1] / (float)n - mu * mu;
    var = var < 0.f ? 0.f : var;
    float inv = 1.0f / (sqrtf(var) + EPSV);
    int i8 = (blockIdx.x * blockDim.x + threadIdx.x) * 8;
    if (i8 >= n) return;
    int c = i8 & (C - 1);
    us8 v = *(const us8*)(h + i8);
    us8 o;
#pragma unroll
    for (int j = 0; j < 8; j++) {
        float y = (bf2f(v[j]) - mu) * inv * g[c + j] + b[c + j];
        o[j] = f2bf(fmaxf(y, 0.f));
    }
    *(us8*)(h + i8) = o;
}

// graph-LN + ReLU + column-sum only (layer 2; h2 not needed afterwards)
__global__ void k_ln_colsum(const unsigned short* __restrict__ h, int n,
                            const float* __restrict__ st,
                            const float* __restrict__ g, const float* __restrict__ b,
                            float* __restrict__ colsum) {
    float mu = st[0] / (float)n;
    float var = st[1] / (float)n - mu * mu;
    var = var < 0.f ? 0.f : var;
    float inv = 1.0f / (sqrtf(var) + EPSV);
    int t = threadIdx.x;
    float gv = g[t], bv = b[t];
    float local = 0.f;
    int stride = gridDim.x * blockDim.x;   // multiple of 256 -> channel == t always
    for (int i = blockIdx.x * blockDim.x + t; i < n; i += stride) {
        float y = (bf2f(h[i]) - mu) * inv * gv + bv;
        local += fmaxf(y, 0.f);
    }
    atomicAdd(&colsum[t], local);
}

// ---------------- head: mean-pool @ Wf + bf -> LN(64) -> relu ----------------
// split-K matvec: 256 threads = 4 k-groups x 64 out-cols (coalesced Wf reads),
// LDS-reduce the 4 partials, then wave-wide LN on 64 lanes.
__global__ void k_final(const float* __restrict__ colsum, const float* __restrict__ Wf,
                        const float* __restrict__ bf, const float* __restrict__ gx,
                        const float* __restrict__ bx, float* __restrict__ out) {
    __shared__ float p[256];
    __shared__ float red[4][64];
    int t = threadIdx.x;
    p[t] = colsum[t] * (1.0f / (float)NODES);
    __syncthreads();
    int kg = t >> 6, o = t & 63;
    float a = 0.f;
#pragma unroll
    for (int j = 0; j < 64; j++) {
        int c = kg + j * 4;
        a = fmaf(p[c], Wf[c * 64 + o], a);
    }
    red[kg][o] = a;
    __syncthreads();
    if (t < 64) {
        float acc = bf[t] + red[0][t] + red[1][t] + red[2][t] + red[3][t];
        float sum = acc;
        for (int w = 32; w > 0; w >>= 1) sum += __shfl_xor(sum, w);
        float mu = sum * (1.0f / 64.0f);
        float d = acc - mu;
        float vs = d * d;
        for (int w = 32; w > 0; w >>= 1) vs += __shfl_xor(vs, w);
        float var = vs * (1.0f / 64.0f);
        float y = d * rsqrtf(var + EPSV) * gx[t] + bx[t];
        out[t] = fmaxf(y, 0.f);
    }
}

extern "C" void kernel_launch(void* const* d_in, const int* in_sizes, int n_in,
                              void* d_out, int out_size, void* d_ws, size_t ws_size,
                              hipStream_t stream) {
    const float* x   = (const float*)d_in[0];
    const int*   ei  = (const int*)d_in[1];
    const float* t1  = (const float*)d_in[2];
    const float* Wl1 = (const float*)d_in[3];
    const float* bl1 = (const float*)d_in[4];
    const float* Wr1 = (const float*)d_in[5];
    const float* g1  = (const float*)d_in[6];
    const float* be1 = (const float*)d_in[7];
    const float* t2  = (const float*)d_in[8];
    const float* Wl2 = (const float*)d_in[9];
    const float* bl2 = (const float*)d_in[10];
    const float* Wr2 = (const float*)d_in[11];
    const float* g2  = (const float*)d_in[12];
    const float* be2 = (const float*)d_in[13];
    const float* Wf  = (const float*)d_in[14];
    const float* bf  = (const float*)d_in[15];
    const float* gx  = (const float*)d_in[16];
    const float* bx  = (const float*)d_in[17];
    float* out = (float*)d_out;

    char* ws = (char*)d_ws;
    size_t off = 0;
    auto alloc = [&](size_t bytes) { size_t o = off; off = (off + bytes + 511) & ~511ull; return o; };
    size_t o_counts = alloc((size_t)NODES * 4);
    size_t o_cursor = alloc((size_t)NODES * 4);
    size_t zero_bytes = off;                         // memset: counts+cursor only
    size_t o_acc    = alloc(4 * 4);
    size_t o_colsum = alloc(256 * 4);
    size_t o_bsum = alloc((size_t)SCAN_B * 4);
    size_t o_offs = alloc((size_t)(NODES + 1) * 4);
    size_t o_csrc = alloc((size_t)EDGES * 4);
    size_t o_w1l  = alloc((size_t)512 * 256 * 2);
    size_t o_w1r  = alloc((size_t)512 * 256 * 2);
    size_t o_w2l  = alloc((size_t)256 * 512 * 2);
    size_t o_w2r  = alloc((size_t)256 * 512 * 2);
    size_t o_bufX = alloc((size_t)MPAD * 256 * 2);   // xb, later h2_pre (bf16)
    size_t o_agg  = alloc((size_t)MPAD * 512 * 2);   // agg1b / agg2b
    size_t o_h1   = alloc((size_t)(MPAD + 512) * 512 * 2); // h1 (+pad-tile slack)

    int*   counts = (int*)(ws + o_counts);
    int*   cursor = (int*)(ws + o_cursor);
    float* acc    = (float*)(ws + o_acc);      // [0,1]=L1 stats, [2,3]=L2 stats
    float* colsum = (float*)(ws + o_colsum);
    int*   bsum   = (int*)(ws + o_bsum);
    int*   offs   = (int*)(ws + o_offs);
    int*   csrc   = (int*)(ws + o_csrc);
    unsigned short* w1lt = (unsigned short*)(ws + o_w1l);
    unsigned short* w1rt = (unsigned short*)(ws + o_w1r);
    unsigned short* w2lt = (unsigned short*)(ws + o_w2l);
    unsigned short* w2rt = (unsigned short*)(ws + o_w2r);
    unsigned short* xb   = (unsigned short*)(ws + o_bufX);
    unsigned short* h2p  = (unsigned short*)(ws + o_bufX);  // reuse after xb dead
    unsigned short* aggb = (unsigned short*)(ws + o_agg);
    unsigned short* h1   = (unsigned short*)(ws + o_h1);

    const int* src = ei;
    const int* dst = ei + EDGES;

    hipMemsetAsync(ws, 0, zero_bytes, stream);

    // D1: fused prep (count + cast + transposes + zero acc/colsum)
    k_prep<<<PREP_TOTAL, 256, 0, stream>>>(dst, counts, x, xb,
                                           Wl1, Wr1, Wl2, Wr2,
                                           w1lt, w1rt, w2lt, w2rt,
                                           acc, colsum);
    // D2-D4: parallel CSR scan, then scatter
    k_scan1<<<SCAN_B, 256, 0, stream>>>(counts, bsum);
    k_scan2<<<1, 64, 0, stream>>>(bsum, offs);
    k_scan3<<<SCAN_B, 256, 0, stream>>>(counts, bsum, offs);
    k_scatter<<<(EDGES + 255) / 256, 256, 0, stream>>>(src, dst, offs, cursor, csrc);

    // ----- layer 1 -----  (2 waves per node, 128 ch each)
    k_agg<256, 2, 8><<<(NODES * 2 + 3) / 4, 256, 0, stream>>>(xb, t1, offs, csrc, aggb);
    k_gemm_mfma<256, 512, 4, 128><<<8 * 4 * 20, 256, 0, stream>>>(
        aggb, w1lt, xb, w1rt, bl1, h1, NODES, acc);
    k_ln_relu_b<512><<<NODES * 512 / 8 / 256, 256, 0, stream>>>(h1, NODES * 512, acc, g1, be1);

    // ----- layer 2 -----  (2 waves per node, 256 ch each)
    k_agg<512, 2, 4><<<(NODES * 2 + 3) / 4, 256, 0, stream>>>(h1, t2, offs, csrc, aggb);
    k_gemm_mfma<512, 256, 2, 128><<<8 * 2 * 20, 256, 0, stream>>>(
        aggb, w2lt, h1, w2rt, bl2, h2p, NODES, acc + 2);

    // ----- LN2 + colsum, then head -----
    k_ln_colsum<<<1024, 256, 0, stream>>>(h2p, NODES * 256, acc + 2, g2, be2, colsum);
    k_final<<<1, 256, 0, stream>>>(colsum, Wf, bf, gx, bx, out);
}

// Round 7
// 315.389 us; speedup vs baseline: 1.0586x; 1.0173x over previous
//
#include <hip/hip_runtime.h>
#include <math.h>

#define NODES 20000
#define MPAD  20096          // NODES padded to multiple of 128 (GEMM M-tiles)
#define EDGES 320000
#define EPSV  1e-5f
#define LOG2E 1.4426950408889634f

// k_prep block ranges
#define PREP_CNT   1250                    // count: 1250*256 >= EDGES
#define PREP_CAST  5000                    // cast: NODES*256/4/256
#define PREP_TR    512                     // 4 matrices * 128 tiles
#define PREP_TOTAL (PREP_CNT + PREP_CAST + PREP_TR + 1)

typedef short bf16x8 __attribute__((ext_vector_type(8)));
typedef float f32x4  __attribute__((ext_vector_type(4)));
typedef float f2     __attribute__((ext_vector_type(2)));

__device__ __forceinline__ unsigned short f2bf(float f) {
    unsigned int u = __float_as_uint(f);
    u = (u + 0x7fffu + ((u >> 16) & 1u)) >> 16;
    return (unsigned short)u;
}
__device__ __forceinline__ float bf2f(unsigned short h) {
    return __uint_as_float(((unsigned int)h) << 16);
}

// ---------------- fused prep: edge-count + x cast + 4x weight transpose + zeros
__global__ void k_prep(const int* __restrict__ dst, int* __restrict__ counts,
                       const float* __restrict__ x, unsigned short* __restrict__ xb,
                       const float* __restrict__ Wl1, const float* __restrict__ Wr1,
                       const float* __restrict__ Wl2, const float* __restrict__ Wr2,
                       unsigned short* __restrict__ o1l, unsigned short* __restrict__ o1r,
                       unsigned short* __restrict__ o2l, unsigned short* __restrict__ o2r,
                       float* __restrict__ acc, float* __restrict__ colsum) {
    int b = blockIdx.x;
    int t = threadIdx.x;
    if (b < PREP_CNT) {
        int e = b * 256 + t;
        if (e < EDGES) atomicAdd(&counts[dst[e]], 1);
    } else if (b < PREP_CNT + PREP_CAST) {
        int i = ((b - PREP_CNT) * 256 + t) * 4;
        float4 v = *(const float4*)(x + i);
        xb[i + 0] = f2bf(v.x); xb[i + 1] = f2bf(v.y);
        xb[i + 2] = f2bf(v.z); xb[i + 3] = f2bf(v.w);
    } else if (b < PREP_CNT + PREP_CAST + PREP_TR) {
        __shared__ float tile[32][33];
        int zz = b - PREP_CNT - PREP_CAST;     // 0..511
        int z = zz >> 7;                        // matrix 0..3
        int idx = zz & 127;                     // tile within matrix
        const float* W = (z == 0) ? Wl1 : (z == 1) ? Wr1 : (z == 2) ? Wl2 : Wr2;
        unsigned short* Wt = (z == 0) ? o1l : (z == 1) ? o1r : (z == 2) ? o2l : o2r;
        int K = (z < 2) ? 256 : 512, N = (z < 2) ? 512 : 256;
        int nb = N / 32;
        int n0 = (idx % nb) * 32, k0 = (idx / nb) * 32;
        int tx = t & 31, ty = t >> 5;          // (32,8) layout
#pragma unroll
        for (int j = 0; j < 4; j++)
            tile[ty + j * 8][tx] = W[(size_t)(k0 + ty + j * 8) * N + n0 + tx];
        __syncthreads();
#pragma unroll
        for (int j = 0; j < 4; j++)
            Wt[(size_t)(n0 + ty + j * 8) * K + k0 + tx] = f2bf(tile[tx][ty + j * 8]);
    } else {
        if (t < 4) acc[t] = 0.f;
        colsum[t] = 0.f;
    }
}

// ---------------- parallel CSR scan (3 small dispatches) + scatter ----------
// Measured fastest scan variant (r2: 318.4us wall). The single-1024-thread-
// block variant (r3/r4) is +8us: counts[t*20+j] loads are 80B-strided
// (uncoalesced) and everything serializes on one CU.
#define SCAN_B 32

__global__ void k_scan1(const int* __restrict__ counts, int* __restrict__ bsum) {
    __shared__ int sm[256];
    int t = threadIdx.x, b = blockIdx.x;
    int i0 = (b * 256 + t) * 3;
    int s = 0;
#pragma unroll
    for (int j = 0; j < 3; j++) { int i = i0 + j; if (i < NODES) s += counts[i]; }
    sm[t] = s;
    __syncthreads();
    int v = s;
#pragma unroll
    for (int o = 1; o < 256; o <<= 1) {
        int add = (t >= o) ? sm[t - o] : 0;
        __syncthreads();
        v += add;
        sm[t] = v;
        __syncthreads();
    }
    if (t == 255) bsum[b] = v;
}

// 1 wave: scan the 32 block sums -> exclusive bases; write offs[NODES]=total
__global__ void k_scan2(int* __restrict__ bsum, int* __restrict__ offs) {
    int t = threadIdx.x;                     // 64 threads = 1 wave
    int v = (t < SCAN_B) ? bsum[t] : 0;
    int x = v;
#pragma unroll
    for (int o = 1; o < 64; o <<= 1) {
        int y = __shfl_up(x, o);
        if (t >= o) x += y;
    }
    if (t < SCAN_B) bsum[t] = x - v;         // exclusive base
    if (t == SCAN_B - 1) offs[NODES] = x;    // grand total
}

__global__ void k_scan3(const int* __restrict__ counts, const int* __restrict__ bsum,
                        int* __restrict__ offs) {
    __shared__ int sm[256];
    int t = threadIdx.x, b = blockIdx.x;
    int i0 = (b * 256 + t) * 3;
    int c[3]; int s = 0;
#pragma unroll
    for (int j = 0; j < 3; j++) {
        int i = i0 + j;
        c[j] = (i < NODES) ? counts[i] : 0;
        s += c[j];
    }
    sm[t] = s;
    __syncthreads();
    int v = s;
#pragma unroll
    for (int o = 1; o < 256; o <<= 1) {
        int add = (t >= o) ? sm[t - o] : 0;
        __syncthreads();
        v += add;
        sm[t] = v;
        __syncthreads();
    }
    int run = bsum[b] + (v - s);             // block base + thread-exclusive
#pragma unroll
    for (int j = 0; j < 3; j++) {
        int i = i0 + j;
        if (i < NODES) { offs[i] = run; run += c[j]; }
    }
}

__global__ void k_scatter(const int* __restrict__ src, const int* __restrict__ dst,
                          const int* __restrict__ offs, int* __restrict__ cursor,
                          int* __restrict__ csr_src) {
    int e = blockIdx.x * blockDim.x + threadIdx.x;
    if (e < EDGES) {
        int d = dst[e];
        int pos = atomicAdd(&cursor[d], 1);
        csr_src[offs[d] + pos] = src[e];
    }
}

// ------- per-channel softmax aggregation, un-stabilized (inputs bounded) -----
// S waves per node (interleaved waveg%S — measured fastest agg variant, r10).
// Wave-uniform CSR walk via readfirstlane: csr[k] -> s_load; vector pipe:
// loop-invariant-offset gather + packed-f32 exp2/fma.
// Measured floor ~44.5us (layer 2): 11 structural variants land 44-50us
// (incl. XCD-pinned channel slicing: fetch 133->60MB but time +2us — the
// kernel is issue/latency-bound, NOT fetch-bound; keep this config).
template <int C, int S, int UNR>
__global__ void k_agg(const unsigned short* __restrict__ xb, const float* __restrict__ tt,
                      const int* __restrict__ offs, const int* __restrict__ csr,
                      unsigned short* __restrict__ out) {
    constexpr int CS  = C / S;
    constexpr int VPL = CS / 64;
    constexpr int W   = VPL / 2;
    typedef unsigned int uv __attribute__((ext_vector_type(W)));
    typedef unsigned short usv __attribute__((ext_vector_type(VPL)));
    int waveg = (int)((blockIdx.x * (unsigned)blockDim.x + threadIdx.x) >> 6);
    int lane = threadIdx.x & 63;
    int node = waveg / S;
    int slice = waveg % S;
    if (node >= NODES) return;
    int beg = __builtin_amdgcn_readfirstlane(offs[node]);
    int end = __builtin_amdgcn_readfirstlane(offs[node + 1]);
    int cb = slice * CS + lane * VPL;
    const unsigned short* __restrict__ xcb = xb + cb;
    f2 tl[W], l[W], s[W];
#pragma unroll
    for (int i = 0; i < W; i++) {
        tl[i][0] = tt[cb + 2 * i] * LOG2E;
        tl[i][1] = tt[cb + 2 * i + 1] * LOG2E;
        l[i][0] = 0.f; l[i][1] = 0.f;
        s[i][0] = 0.f; s[i][1] = 0.f;
    }
    int k = beg;
    for (; k + UNR <= end; k += UNR) {
        uv v[UNR];
#pragma unroll
        for (int u = 0; u < UNR; u++) {
            int sn = csr[k + u];                     // uniform -> s_load
            v[u] = *(const uv*)(xcb + (size_t)sn * C);
        }
#pragma unroll
        for (int u = 0; u < UNR; u++)
#pragma unroll
            for (int i = 0; i < W; i++) {
                unsigned wd = v[u][i];
                f2 xv;
                xv[0] = __uint_as_float(wd << 16);
                xv[1] = __uint_as_float(wd & 0xffff0000u);
                f2 a = xv * tl[i];
                f2 p;
                p[0] = __builtin_amdgcn_exp2f(a[0]);
                p[1] = __builtin_amdgcn_exp2f(a[1]);
                l[i] += p;
                s[i] = __builtin_elementwise_fma(p, xv, s[i]);
            }
    }
    for (; k < end; k++) {
        int sn = csr[k];
        uv vv = *(const uv*)(xcb + (size_t)sn * C);
#pragma unroll
        for (int i = 0; i < W; i++) {
            unsigned wd = vv[i];
            f2 xv;
            xv[0] = __uint_as_float(wd << 16);
            xv[1] = __uint_as_float(wd & 0xffff0000u);
            f2 a = xv * tl[i];
            f2 p;
            p[0] = __builtin_amdgcn_exp2f(a[0]);
            p[1] = __builtin_amdgcn_exp2f(a[1]);
            l[i] += p;
            s[i] = __builtin_elementwise_fma(p, xv, s[i]);
        }
    }
    bool has = end > beg;
    usv o;
#pragma unroll
    for (int i = 0; i < W; i++) {
        o[2 * i]     = f2bf(has ? s[i][0] / l[i][0] : 0.f);
        o[2 * i + 1] = f2bf(has ? s[i][1] / l[i][1] : 0.f);
    }
    *(usv*)(out + (size_t)node * C + cb) = o;
}

// ---------------- dual bf16 MFMA GEMM: C = A1*B1t^T + A2*B2t^T + bias ---------
// Tile 128x128, REG-STAGED prefetch pipeline (T14). r5/r6 PMC: every
// global_load_lds structural variant lands at 44-45us with all pipes ~90%
// idle — per-load ~650cy serialized (LDS-DMA path has shallow outstanding
// depth per wave). Fix: load slab to VGPRs (global_load_dwordx4, vmcnt
// depth 63 -> all 8 loads truly in flight), ds_write_b128 into the SAME
// LDS layout, and issue slab s+1's loads BEFORE computing slab s so the
// MFMA phase covers the latency once per slab. BK=64 (2x32 chunks/slab).
// Thread t's 16B -> As[c*4096 + it*2048 + t*8] == old load_lds16 dest.
// XCD-affinity swizzle: all NTILES n-variants of one m-tile share bx%8.
// LN sum/sumsq fused into epilogue (wave shfl-reduce, 1 barrier).
template <int K, int NT, int NTILES, int TN>
__global__ __launch_bounds__(256) void k_gemm_mfma(
    const unsigned short* __restrict__ A1, const unsigned short* __restrict__ B1t,
    const unsigned short* __restrict__ A2, const unsigned short* __restrict__ B2t,
    const float* __restrict__ bias, unsigned short* __restrict__ Co, int M,
    float* __restrict__ stat) {
    constexpr int NF  = TN / 32;           // n-frags per wave (2 waves span TN)
    constexpr int BIT = TN / 64;           // B row-groups per chunk
    constexpr int HS  = K / 64;            // slabs per phase
    constexpr int NS  = 2 * HS;            // total slabs (both phases)
    __shared__ short As[2 * 128 * 32];     // 2 k-chunks, [128][32] each
    __shared__ short Bs[2 * TN * 32];
    __shared__ float rs[8], rq[8];

    // swizzled decode: bx = x + 8*(n + NTILES*mh); m = mh*8 + x
    int bx = blockIdx.x;
    int xid = bx & 7, q = bx >> 3;
    int n = q % NTILES, mh = q / NTILES;
    int m = mh * 8 + xid;
    if (m * 128 >= MPAD) return;           // pad tiles: whole block exits
    int m0 = m * 128, n0 = n * TN;

    int t = threadIdx.x;
    int wv = t >> 6, lane = t & 63;
    int wm = wv & 1, wn = wv >> 1;
    int lm = lane & 15, quad = lane >> 4;
    int sr = t >> 2;
    int sc8 = (t & 3) * 8;

    f32x4 acc[4][NF] = {};
    bf16x8 rA[2][2];                       // [chunk][rowgroup] prefetch regs
    bf16x8 rB[2][BIT];

    auto loadslab = [&](int s) {
        const unsigned short* __restrict__ A  = (s < HS) ? A1 : A2;
        const unsigned short* __restrict__ Bt = (s < HS) ? B1t : B2t;
        int kk = (s & (HS - 1)) * 64;
#pragma unroll
        for (int c = 0; c < 2; c++) {
#pragma unroll
            for (int it = 0; it < 2; it++)
                rA[c][it] = *(const bf16x8*)(A + (size_t)(m0 + it * 64 + sr) * K + kk + c * 32 + sc8);
#pragma unroll
            for (int it = 0; it < BIT; it++)
                rB[c][it] = *(const bf16x8*)(Bt + (size_t)(n0 + it * 64 + sr) * K + kk + c * 32 + sc8);
        }
    };

    loadslab(0);
    for (int s = 0; s < NS; s++) {
        if (s) __syncthreads();            // all waves done reading LDS of s-1
#pragma unroll
        for (int c = 0; c < 2; c++) {      // regs -> LDS (vmcnt wait auto)
#pragma unroll
            for (int it = 0; it < 2; it++)
                *(bf16x8*)&As[c * 4096 + it * 2048 + t * 8] = rA[c][it];
#pragma unroll
            for (int it = 0; it < BIT; it++)
                *(bf16x8*)&Bs[c * (TN * 32) + it * 2048 + t * 8] = rB[c][it];
        }
        __syncthreads();                   // slab visible to all waves
        if (s + 1 < NS) loadslab(s + 1);   // prefetch flies under compute
#pragma unroll
        for (int c = 0; c < 2; c++) {
            bf16x8 af[4], bfr[NF];
#pragma unroll
            for (int i = 0; i < 4; i++)
                af[i] = *(const bf16x8*)&As[c * 4096 + (wm * 64 + i * 16 + lm) * 32 + quad * 8];
#pragma unroll
            for (int j = 0; j < NF; j++)
                bfr[j] = *(const bf16x8*)&Bs[c * (TN * 32) + (wn * (TN / 2) + j * 16 + lm) * 32 + quad * 8];
#pragma unroll
            for (int mi = 0; mi < 4; mi++)
#pragma unroll
                for (int nj = 0; nj < NF; nj++)
                    acc[mi][nj] = __builtin_amdgcn_mfma_f32_16x16x32_bf16(
                        af[mi], bfr[nj], acc[mi][nj], 0, 0, 0);
        }
    }

    float sum = 0.f, ss = 0.f;
#pragma unroll
    for (int mi = 0; mi < 4; mi++) {
        int rb = m0 + wm * 64 + mi * 16 + quad * 4;
#pragma unroll
        for (int nj = 0; nj < NF; nj++) {
            int col = n0 + wn * (TN / 2) + nj * 16 + lm;
            float bb = bias[col];
#pragma unroll
            for (int rg = 0; rg < 4; rg++) {
                int row = rb + rg;
                if (row < M) {
                    float y = acc[mi][nj][rg] + bb;
                    Co[(size_t)row * NT + col] = f2bf(y);
                    sum += y; ss += y * y;
                }
            }
        }
    }
    // wave shfl-reduce, then 1 barrier + single atomic pair per block
#pragma unroll
    for (int o = 32; o > 0; o >>= 1) {
        sum += __shfl_xor(sum, o);
        ss  += __shfl_xor(ss, o);
    }
    if (lane == 0) { rs[wv] = sum; rq[wv] = ss; }
    __syncthreads();
    if (t == 0) {
        float a0 = 0.f, a1 = 0.f;
#pragma unroll
        for (int i = 0; i < 4; i++) { a0 += rs[i] + rs[i + 4]; a1 += rq[i] + rq[i + 4]; }
        atomicAdd(&stat[0], a0); atomicAdd(&stat[1], a1);
    }
}

// ---------------- graph-LN + ReLU, in-place bf16, vectorized x8 --------------
template <int C>
__global__ void k_ln_relu_b(unsigned short* __restrict__ h, int n,
                            const float* __restrict__ st,
                            const float* __restrict__ g, const float* __restrict__ b) {
    typedef unsigned short us8 __attribute__((ext_vector_type(8)));
    float mu = st[0] / (float)n;
    float var = st[1] / (float)n - mu * mu;
    var = var < 0.f ? 0.f : var;
    float inv = 1.0f / (sqrtf(var) + EPSV);
    int i8 = (blockIdx.x * blockDim.x + threadIdx.x) * 8;
    if (i8 >= n) return;
    int c = i8 & (C - 1);
    us8 v = *(const us8*)(h + i8);
    us8 o;
#pragma unroll
    for (int j = 0; j < 8; j++) {
        float y = (bf2f(v[j]) - mu) * inv * g[c + j] + b[c + j];
        o[j] = f2bf(fmaxf(y, 0.f));
    }
    *(us8*)(h + i8) = o;
}

// graph-LN + ReLU + column-sum only (layer 2; h2 not needed afterwards)
__global__ void k_ln_colsum(const unsigned short* __restrict__ h, int n,
                            const float* __restrict__ st,
                            const float* __restrict__ g, const float* __restrict__ b,
                            float* __restrict__ colsum) {
    float mu = st[0] / (float)n;
    float var = st[1] / (float)n - mu * mu;
    var = var < 0.f ? 0.f : var;
    float inv = 1.0f / (sqrtf(var) + EPSV);
    int t = threadIdx.x;
    float gv = g[t], bv = b[t];
    float local = 0.f;
    int stride = gridDim.x * blockDim.x;   // multiple of 256 -> channel == t always
    for (int i = blockIdx.x * blockDim.x + t; i < n; i += stride) {
        float y = (bf2f(h[i]) - mu) * inv * gv + bv;
        local += fmaxf(y, 0.f);
    }
    atomicAdd(&colsum[t], local);
}

// ---------------- head: mean-pool @ Wf + bf -> LN(64) -> relu ----------------
// split-K matvec: 256 threads = 4 k-groups x 64 out-cols (coalesced Wf reads),
// LDS-reduce the 4 partials, then wave-wide LN on 64 lanes.
__global__ void k_final(const float* __restrict__ colsum, const float* __restrict__ Wf,
                        const float* __restrict__ bf, const float* __restrict__ gx,
                        const float* __restrict__ bx, float* __restrict__ out) {
    __shared__ float p[256];
    __shared__ float red[4][64];
    int t = threadIdx.x;
    p[t] = colsum[t] * (1.0f / (float)NODES);
    __syncthreads();
    int kg = t >> 6, o = t & 63;
    float a = 0.f;
#pragma unroll
    for (int j = 0; j < 64; j++) {
        int c = kg + j * 4;
        a = fmaf(p[c], Wf[c * 64 + o], a);
    }
    red[kg][o] = a;
    __syncthreads();
    if (t < 64) {
        float acc = bf[t] + red[0][t] + red[1][t] + red[2][t] + red[3][t];
        float sum = acc;
        for (int w = 32; w > 0; w >>= 1) sum += __shfl_xor(sum, w);
        float mu = sum * (1.0f / 64.0f);
        float d = acc - mu;
        float vs = d * d;
        for (int w = 32; w > 0; w >>= 1) vs += __shfl_xor(vs, w);
        float var = vs * (1.0f / 64.0f);
        float y = d * rsqrtf(var + EPSV) * gx[t] + bx[t];
        out[t] = fmaxf(y, 0.f);
    }
}

extern "C" void kernel_launch(void* const* d_in, const int* in_sizes, int n_in,
                              void* d_out, int out_size, void* d_ws, size_t ws_size,
                              hipStream_t stream) {
    const float* x   = (const float*)d_in[0];
    const int*   ei  = (const int*)d_in[1];
    const float* t1  = (const float*)d_in[2];
    const float* Wl1 = (const float*)d_in[3];
    const float* bl1 = (const float*)d_in[4];
    const float* Wr1 = (const float*)d_in[5];
    const float* g1  = (const float*)d_in[6];
    const float* be1 = (const float*)d_in[7];
    const float* t2  = (const float*)d_in[8];
    const float* Wl2 = (const float*)d_in[9];
    const float* bl2 = (const float*)d_in[10];
    const float* Wr2 = (const float*)d_in[11];
    const float* g2  = (const float*)d_in[12];
    const float* be2 = (const float*)d_in[13];
    const float* Wf  = (const float*)d_in[14];
    const float* bf  = (const float*)d_in[15];
    const float* gx  = (const float*)d_in[16];
    const float* bx  = (const float*)d_in[17];
    float* out = (float*)d_out;

    char* ws = (char*)d_ws;
    size_t off = 0;
    auto alloc = [&](size_t bytes) { size_t o = off; off = (off + bytes + 511) & ~511ull; return o; };
    size_t o_counts = alloc((size_t)NODES * 4);
    size_t o_cursor = alloc((size_t)NODES * 4);
    size_t zero_bytes = off;                         // memset: counts+cursor only
    size_t o_acc    = alloc(4 * 4);
    size_t o_colsum = alloc(256 * 4);
    size_t o_bsum = alloc((size_t)SCAN_B * 4);
    size_t o_offs = alloc((size_t)(NODES + 1) * 4);
    size_t o_csrc = alloc((size_t)EDGES * 4);
    size_t o_w1l  = alloc((size_t)512 * 256 * 2);
    size_t o_w1r  = alloc((size_t)512 * 256 * 2);
    size_t o_w2l  = alloc((size_t)256 * 512 * 2);
    size_t o_w2r  = alloc((size_t)256 * 512 * 2);
    size_t o_bufX = alloc((size_t)MPAD * 256 * 2);   // xb, later h2_pre (bf16)
    size_t o_agg  = alloc((size_t)MPAD * 512 * 2);   // agg1b / agg2b
    size_t o_h1   = alloc((size_t)(MPAD + 512) * 512 * 2); // h1 (+pad-tile slack)

    int*   counts = (int*)(ws + o_counts);
    int*   cursor = (int*)(ws + o_cursor);
    float* acc    = (float*)(ws + o_acc);      // [0,1]=L1 stats, [2,3]=L2 stats
    float* colsum = (float*)(ws + o_colsum);
    int*   bsum   = (int*)(ws + o_bsum);
    int*   offs   = (int*)(ws + o_offs);
    int*   csrc   = (int*)(ws + o_csrc);
    unsigned short* w1lt = (unsigned short*)(ws + o_w1l);
    unsigned short* w1rt = (unsigned short*)(ws + o_w1r);
    unsigned short* w2lt = (unsigned short*)(ws + o_w2l);
    unsigned short* w2rt = (unsigned short*)(ws + o_w2r);
    unsigned short* xb   = (unsigned short*)(ws + o_bufX);
    unsigned short* h2p  = (unsigned short*)(ws + o_bufX);  // reuse after xb dead
    unsigned short* aggb = (unsigned short*)(ws + o_agg);
    unsigned short* h1   = (unsigned short*)(ws + o_h1);

    const int* src = ei;
    const int* dst = ei + EDGES;

    hipMemsetAsync(ws, 0, zero_bytes, stream);

    // D1: fused prep (count + cast + transposes + zero acc/colsum)
    k_prep<<<PREP_TOTAL, 256, 0, stream>>>(dst, counts, x, xb,
                                           Wl1, Wr1, Wl2, Wr2,
                                           w1lt, w1rt, w2lt, w2rt,
                                           acc, colsum);
    // D2-D4: parallel CSR scan, then scatter
    k_scan1<<<SCAN_B, 256, 0, stream>>>(counts, bsum);
    k_scan2<<<1, 64, 0, stream>>>(bsum, offs);
    k_scan3<<<SCAN_B, 256, 0, stream>>>(counts, bsum, offs);
    k_scatter<<<(EDGES + 255) / 256, 256, 0, stream>>>(src, dst, offs, cursor, csrc);

    // ----- layer 1 -----  (2 waves per node, 128 ch each)
    k_agg<256, 2, 8><<<(NODES * 2 + 3) / 4, 256, 0, stream>>>(xb, t1, offs, csrc, aggb);
    k_gemm_mfma<256, 512, 4, 128><<<8 * 4 * 20, 256, 0, stream>>>(
        aggb, w1lt, xb, w1rt, bl1, h1, NODES, acc);
    k_ln_relu_b<512><<<NODES * 512 / 8 / 256, 256, 0, stream>>>(h1, NODES * 512, acc, g1, be1);

    // ----- layer 2 -----  (2 waves per node, 256 ch each)
    k_agg<512, 2, 4><<<(NODES * 2 + 3) / 4, 256, 0, stream>>>(h1, t2, offs, csrc, aggb);
    k_gemm_mfma<512, 256, 2, 128><<<8 * 2 * 20, 256, 0, stream>>>(
        aggb, w2lt, h1, w2rt, bl2, h2p, NODES, acc + 2);

    // ----- LN2 + colsum, then head -----
    k_ln_colsum<<<1024, 256, 0, stream>>>(h2p, NODES * 256, acc + 2, g2, be2, colsum);
    k_final<<<1, 256, 0, stream>>>(colsum, Wf, bf, gx, bx, out);
}